// Round 1
// baseline (304.416 us; speedup 1.0000x reference)
//
#include <hip/hip_runtime.h>
#include <hip/hip_bf16.h>
#include <math.h>

#define BATCH 8
#define SEQ 384
#define DIM 768
#define NH 12
#define DH 64
#define NPOS 767
#define POS_OFF 128
#define NTOK (BATCH * SEQ)
#define QKN 1536
#define QKVN 2304
#define PN 1536

typedef __attribute__((ext_vector_type(8))) short short8;
typedef __attribute__((ext_vector_type(4))) float floatx4;
typedef unsigned int u32;

__device__ __forceinline__ ushort f2bf(float f) {
    __hip_bfloat16 h = __float2bfloat16(f);
    return *reinterpret_cast<ushort*>(&h);
}
__device__ __forceinline__ float bf2f(ushort u) {
    u32 x = ((u32)u) << 16;
    float f; __builtin_memcpy(&f, &x, 4); return f;
}

// async global->LDS, 16B per lane; lds dest = wave-uniform base + lane*16
__device__ __forceinline__ void gld16(const ushort* g, ushort* l) {
    __builtin_amdgcn_global_load_lds(
        (const __attribute__((address_space(1))) u32*)g,
        (__attribute__((address_space(3))) u32*)l, 16, 0, 0);
}

#define MFMA __builtin_amdgcn_mfma_f32_16x16x32_bf16

// ---------- prep: weight transposes (z<6) + row converts (z==6) -----------
__global__ __launch_bounds__(256) void prep(
    const float* W0, const float* W1, const float* W2,
    const float* W3, const float* W4, const float* W5,
    const float* x, const float* rpe,
    ushort* __restrict__ wsT, ushort* __restrict__ xb, ushort* __restrict__ rpeb)
{
    const int tid = threadIdx.x;
    if (blockIdx.z < 6) {
        __shared__ float t[64][65];
        const float* srcs[6] = {W0, W1, W2, W3, W4, W5};
        const float* in = srcs[blockIdx.z];
        ushort* out = wsT + (size_t)blockIdx.z * DIM * DIM;
        const int r0 = blockIdx.y * 64, c0 = blockIdx.x * 64;
        for (int p = 0; p < 16; ++p) {
            int e = tid + p * 256, i = e >> 6, j = e & 63;
            t[i][j] = in[(size_t)(r0 + i) * DIM + c0 + j];
        }
        __syncthreads();
        for (int p = 0; p < 16; ++p) {
            int e = tid + p * 256, i = e >> 6, j = e & 63;
            out[(size_t)(c0 + i) * DIM + r0 + j] = f2bf(t[j][i]);
        }
    } else {
        const int n4x = NTOK * DIM / 4;
        const int n4p = NPOS * DIM / 4;
        const int fb = blockIdx.y * 12 + blockIdx.x;      // 0..143
        for (int idx = fb * 256 + tid; idx < n4x + n4p; idx += 144 * 256) {
            const float* src; ushort* dst; int j;
            if (idx < n4x) { src = x; dst = xb; j = idx; }
            else { src = rpe + (size_t)POS_OFF * DIM; dst = rpeb; j = idx - n4x; }
            float4 f = ((const float4*)src)[j];
            ushort o[4] = {f2bf(f.x), f2bf(f.y), f2bf(f.z), f2bf(f.w)};
            *(uint2*)&dst[(size_t)j * 4] = *(uint2*)o;
        }
    }
}

// ---------- combined projections: QKV (blocks 0..431) + pos (432..503) ----
__global__ __launch_bounds__(256) void proj_all(
    const ushort* __restrict__ xb, const ushort* __restrict__ rpeb,
    const ushort* __restrict__ wsT,
    const float* __restrict__ bq, const float* __restrict__ qbias,
    const float* __restrict__ bk, const float* __restrict__ bv,
    const float* __restrict__ vbias,
    ushort* __restrict__ qk, ushort* __restrict__ vT, ushort* __restrict__ posKQ)
{
    __shared__ ushort As[128 * 64];
    __shared__ ushort Bs[128 * 64];
    const int tid = threadIdx.x;
    const int lane = tid & 63, w = tid >> 6;
    const int id = blockIdx.x;
    const bool qkvP = id < 432;
    const ushort* A; const ushort* Bt; int m0, n0, M;
    if (qkvP) {
        m0 = (id % 24) * 128; n0 = (id / 24) * 128;
        A = xb; Bt = wsT; M = NTOK;
    } else {
        int p = id - 432;
        m0 = (p % 6) * 128; n0 = (p / 6) * 128;
        A = rpeb; Bt = wsT + (size_t)3 * DIM * DIM; M = NPOS;
    }
    const int lr = lane >> 3;
    const int lc = (lane & 7) ^ (lr & 7);
    const ushort* ga[4]; const ushort* gb[4];
#pragma unroll
    for (int p = 0; p < 4; ++p) {
        int row = (w * 4 + p) * 8 + lr;
        int arow = m0 + row; if (arow > M - 1) arow = M - 1;
        ga[p] = A + (size_t)arow * DIM + lc * 8;
        gb[p] = Bt + (size_t)(n0 + row) * DIM + lc * 8;
    }
    floatx4 acc[4][4] = {};
    const int qr = (w >> 1) * 64, qc = (w & 1) * 64;
    const int lm = lane & 15, lk = lane >> 4;
    for (int k0 = 0; k0 < DIM; k0 += 64) {
#pragma unroll
        for (int p = 0; p < 4; ++p) {
            gld16(ga[p], As + (w * 4 + p) * 512);
            gld16(gb[p], Bs + (w * 4 + p) * 512);
            ga[p] += 64; gb[p] += 64;
        }
        __syncthreads();
#pragma unroll
        for (int kk = 0; kk < 2; ++kk) {
            int ch = (kk * 4 + lk) ^ (lm & 7);
            short8 af[4], bf[4];
#pragma unroll
            for (int t = 0; t < 4; ++t) {
                af[t] = *(const short8*)&As[(qr + t * 16 + lm) * 64 + ch * 8];
                bf[t] = *(const short8*)&Bs[(qc + t * 16 + lm) * 64 + ch * 8];
            }
#pragma unroll
            for (int i = 0; i < 4; ++i)
#pragma unroll
                for (int j = 0; j < 4; ++j)
                    acc[i][j] = MFMA(af[i], bf[j], acc[i][j], 0, 0, 0);
        }
        __syncthreads();
    }
    if (qkvP) {
#pragma unroll
        for (int i = 0; i < 4; ++i) {
            int mbase = m0 + qr + i * 16 + (lane >> 4) * 4;
            int bb = mbase / SEQ;
            int s0 = mbase - bb * SEQ;
#pragma unroll
            for (int j = 0; j < 4; ++j) {
                int n = n0 + qc + j * 16 + lm;
                float bs;
                if (n < 768) bs = bq[n] + qbias[n];
                else if (n < QKN) bs = bk[n - 768];
                else bs = bv[n - QKN] + vbias[n - QKN];
                if (n < QKN) {
#pragma unroll
                    for (int r = 0; r < 4; ++r)
                        qk[(size_t)(mbase + r) * QKN + n] = f2bf(acc[i][j][r] + bs);
                } else {
                    int c = n - QKN, h = c >> 6, d = c & 63;
                    ushort tmp[4];
#pragma unroll
                    for (int r = 0; r < 4; ++r) tmp[r] = f2bf(acc[i][j][r] + bs);
                    *(uint2*)&vT[(((size_t)bb * NH + h) * DH + d) * SEQ + s0] = *(uint2*)tmp;
                }
            }
        }
    } else {
#pragma unroll
        for (int i = 0; i < 4; ++i) {
            int mbase = m0 + qr + i * 16 + (lane >> 4) * 4;
#pragma unroll
            for (int j = 0; j < 4; ++j) {
                int n = n0 + qc + j * 16 + lm;
#pragma unroll
                for (int r = 0; r < 4; ++r) {
                    int row = mbase + r;
                    if (row < NPOS)
                        posKQ[(size_t)row * PN + n] = f2bf(acc[i][j][r]);
                }
            }
        }
    }
}

// ---------- 128x64-tile MFMA GEMM (output projection, 288 blocks) ---------
__global__ __launch_bounds__(256) void gemm128x64(
    const ushort* __restrict__ A, const ushort* __restrict__ Bt,
    const float* __restrict__ bias, float* __restrict__ outF,
    int M, int N, int K)
{
    __shared__ ushort As[128 * 64];
    __shared__ ushort Bs[64 * 64];
    const int tid = threadIdx.x;
    const int lane = tid & 63, w = tid >> 6;
    const int n0 = blockIdx.x * 64, m0 = blockIdx.y * 128;
    const int lr = lane >> 3;
    const int lc = (lane & 7) ^ (lr & 7);
    const ushort* ga[4]; const ushort* gb[2];
#pragma unroll
    for (int p = 0; p < 4; ++p) {
        int arow = m0 + (w * 4 + p) * 8 + lr; if (arow > M - 1) arow = M - 1;
        ga[p] = A + (size_t)arow * K + lc * 8;
    }
#pragma unroll
    for (int p = 0; p < 2; ++p)
        gb[p] = Bt + (size_t)(n0 + (w * 2 + p) * 8 + lr) * K + lc * 8;
    floatx4 acc[4][2] = {};
    const int qr = (w >> 1) * 64, qc = (w & 1) * 32;
    const int lm = lane & 15, lk = lane >> 4;
    for (int k0 = 0; k0 < K; k0 += 64) {
#pragma unroll
        for (int p = 0; p < 4; ++p) { gld16(ga[p], As + (w * 4 + p) * 512); ga[p] += 64; }
#pragma unroll
        for (int p = 0; p < 2; ++p) { gld16(gb[p], Bs + (w * 2 + p) * 512); gb[p] += 64; }
        __syncthreads();
#pragma unroll
        for (int kk = 0; kk < 2; ++kk) {
            int ch = (kk * 4 + lk) ^ (lm & 7);
            short8 af[4], bf[2];
#pragma unroll
            for (int t = 0; t < 4; ++t)
                af[t] = *(const short8*)&As[(qr + t * 16 + lm) * 64 + ch * 8];
#pragma unroll
            for (int t = 0; t < 2; ++t)
                bf[t] = *(const short8*)&Bs[(qc + t * 16 + lm) * 64 + ch * 8];
#pragma unroll
            for (int i = 0; i < 4; ++i)
#pragma unroll
                for (int j = 0; j < 2; ++j)
                    acc[i][j] = MFMA(af[i], bf[j], acc[i][j], 0, 0, 0);
        }
        __syncthreads();
    }
#pragma unroll
    for (int i = 0; i < 4; ++i) {
        int mbase = m0 + qr + i * 16 + (lane >> 4) * 4;
#pragma unroll
        for (int j = 0; j < 2; ++j) {
            int n = n0 + qc + j * 16 + lm;
            float bs = bias[n];
#pragma unroll
            for (int r = 0; r < 4; ++r) {
                int row = mbase + r;
                if (row < M) outF[(size_t)row * N + n] = acc[i][j][r] + bs;
            }
        }
    }
}

// ---------- fused attention v9: Kp/Qp fragments direct from global --------
// grid (6, 12, 8), 512 threads (8 waves). LDS cut 76.5KB -> 44.25KB so
// 3 blocks/CU fit (capacity 768 >= 576 blocks: single-round makespan).
// posKQ is 2.3MB and shared by 48 blocks per head -> L2-resident, so the
// dq B-frags and dk A-frag are loaded straight to registers (the staged-LDS
// deswizzle ch=(kk*4+lq)^(lm&7) collapses to plain chunk (kk*4+lq)).
// Only the k-tile is still LDS-staged (reused by all 8 waves, 3 phases).
// t=767 overread (i0=0, jt=5) lands in wsT pad; outputs band-masked.
__global__ __launch_bounds__(512, 6) void attn_fused9(
    const ushort* __restrict__ qk, const ushort* __restrict__ vT,
    const ushort* __restrict__ posKQ, ushort* __restrict__ aob)
{
    __shared__ ushort kt[64 * 64];        // 8 KB  k tile (swizzled)
    __shared__ ushort ccpt[2][64 * 72];   // 18 KB c2c scores / P (in-place), dbuf
    __shared__ ushort dqs[64 * 72];       // 9 KB  dq pre-shifted: [i][j]=dq[i][j-i+63]
    __shared__ ushort dks[64 * 72];       // 9 KB  dk pre-shifted: [i][j]=dk[j-i+63][j]
    __shared__ float rowsum[64];

    const int tid = threadIdx.x;
    const int lane = tid & 63, w = tid >> 6;
    const int i0 = blockIdx.x * 64;
    const int h = blockIdx.y, b = blockIdx.z;
    const int lm = lane & 15, lq = lane >> 4;
    const int lr = lane >> 3, l8 = lane & 7;
    const int lc = l8 ^ (lr & 7);                 // swizzled source chunk
    const int exr = tid >> 3, exseg = tid & 7;    // 64 rows x 8 segs (phase C)

    if (tid < 64) rowsum[tid] = 0.f;

    // q fragments: register-resident (i-tile w>>1; two waves share a tile)
    short8 qf[2];
    {
        const ushort* qr = qk + (size_t)(b * SEQ + i0 + (w >> 1) * 16 + lm) * QKN + h * DH;
        qf[0] = *(const short8*)(qr + lq * 8);
        qf[1] = *(const short8*)(qr + 32 + lq * 8);
    }
    const ushort* kb = qk + 768 + h * DH;
    floatx4 occ[2] = {};

    // per-thread global fragment pointers into posKQ (advance 64*PN per jt)
    const int t0i = 0 - i0 + 320;
    const int tcb = (w & 1) * 4;
    const ushort* kp_p[4];
#pragma unroll
    for (int s = 0; s < 4; ++s)
        kp_p[s] = posKQ + (size_t)(t0i + (tcb + s) * 16 + lm) * PN + h * DH + lq * 8;
    const ushort* qp_p = posKQ + (size_t)(t0i + w * 16 + lm) * PN + 768 + h * DH + lq * 8;

    // stage j-tile 0 (k only)
    gld16(kb + (size_t)(b * SEQ + 8 * w + lr) * QKN + lc * 8, kt + w * 512);

    for (int jt = 0; jt < 6; ++jt) {
        const int j0 = jt * 64;
        ushort* cc = ccpt[jt & 1];

        // issue this iter's Kp/Qp fragment loads (global, L2-hot) so their
        // latency overlaps the barrier wait + c2c's LDS phase
        short8 kpf[2][4];
        short8 qpf[2];
#pragma unroll
        for (int kk = 0; kk < 2; ++kk) {
#pragma unroll
            for (int s = 0; s < 4; ++s)
                kpf[kk][s] = *(const short8*)(kp_p[s] + kk * 32);
            qpf[kk] = *(const short8*)(qp_p + kk * 32);
        }

        __syncthreads();        // (1) kt staged; prev C (dqs/dks) + PV (other cc) done

        // ---- phase B: c2c + dq + dk -> bf16 buffers, unique writers ----
        { // c2c: i-tile w>>1 x j-tiles (w&1)*2+{0,1}
            int tr = w >> 1, tjb = (w & 1) * 2;
            floatx4 a[2] = {};
#pragma unroll
            for (int kk = 0; kk < 2; ++kk) {
                int ch = (kk * 4 + lq) ^ (lm & 7);
                short8 b0 = *(const short8*)&kt[(tjb * 16 + lm) * 64 + ch * 8];
                short8 b1 = *(const short8*)&kt[((tjb + 1) * 16 + lm) * 64 + ch * 8];
                a[0] = MFMA(qf[kk], b0, a[0], 0, 0, 0);
                a[1] = MFMA(qf[kk], b1, a[1], 0, 0, 0);
            }
#pragma unroll
            for (int s = 0; s < 2; ++s) {
                int j = (tjb + s) * 16 + lm;
#pragma unroll
                for (int r = 0; r < 4; ++r)
                    cc[(tr * 16 + lq * 4 + r) * 72 + j] = f2bf(a[s][r]);
            }
        }
        { // dq: i-tile w>>1 x t-tiles (w&1)*4+{0..3}, diag pre-shift store
            int tr = w >> 1;
            floatx4 d[4] = {};
#pragma unroll
            for (int kk = 0; kk < 2; ++kk)
#pragma unroll
                for (int s = 0; s < 4; ++s)
                    d[s] = MFMA(qf[kk], kpf[kk][s], d[s], 0, 0, 0);
#pragma unroll
            for (int s = 0; s < 4; ++s) {
                int t = (tcb + s) * 16 + lm;
#pragma unroll
                for (int r = 0; r < 4; ++r) {
                    int i = tr * 16 + lq * 4 + r;
                    int j = t + i - 63;
                    if ((unsigned)j < 64u) dqs[i * 72 + j] = f2bf(d[s][r]);
                }
            }
        }
        { // dk: t-tile w x j-tiles {0..3}, diag pre-shift store
            floatx4 e[4] = {};
#pragma unroll
            for (int kk = 0; kk < 2; ++kk) {
                int ch = (kk * 4 + lq) ^ (lm & 7);
#pragma unroll
                for (int s = 0; s < 4; ++s) {
                    short8 bf = *(const short8*)&kt[(s * 16 + lm) * 64 + ch * 8];
                    e[s] = MFMA(qpf[kk], bf, e[s], 0, 0, 0);
                }
            }
#pragma unroll
            for (int s = 0; s < 4; ++s) {
                int j = s * 16 + lm;
#pragma unroll
                for (int r = 0; r < 4; ++r) {
                    int t = w * 16 + lq * 4 + r;
                    int i = j - t + 63;
                    if ((unsigned)i < 64u) dks[i * 72 + j] = f2bf(e[s][r]);
                }
            }
        }
        __syncthreads();        // (2) B done; kt free

        // issue next iter's k staging (overlaps phases C and D)
        if (jt < 5) {
            gld16(kb + (size_t)(b * SEQ + j0 + 64 + 8 * w + lr) * QKN + lc * 8, kt + w * 512);
        }
        // advance pos fragment pointers
#pragma unroll
        for (int s = 0; s < 4; ++s) kp_p[s] += 64 * PN;
        qp_p += 64 * PN;

        // ---- phase C: gather 3 terms (b128), exp, rowsum, P in place ----
        {
            int off = exr * 72 + exseg * 8;
            uint4 c4 = *(const uint4*)&cc[off];
            uint4 q4 = *(const uint4*)&dqs[off];
            uint4 k4 = *(const uint4*)&dks[off];
            const ushort* cu = (const ushort*)&c4;
            const ushort* qu = (const ushort*)&q4;
            const ushort* ku = (const ushort*)&k4;
            float psum = 0.f;
            ushort pv[8];
#pragma unroll
            for (int c = 0; c < 8; ++c) {
                float sv = (bf2f(cu[c]) + bf2f(qu[c]) + bf2f(ku[c])) * 0.125f;
                float pe = __expf(sv);
                psum += pe;
                pv[c] = f2bf(pe);
            }
            psum += __shfl_xor(psum, 1);
            psum += __shfl_xor(psum, 2);
            psum += __shfl_xor(psum, 4);
            if (exseg == 0) rowsum[exr] += psum;
            *(uint4*)&cc[off] = *(uint4*)pv;
        }
        __syncthreads();        // (3) P visible

        // ---- phase D: PV accumulate; v direct-to-register -------------
        {
            int tr = w >> 1, dtb = (w & 1) * 2;
#pragma unroll
            for (int t2 = 0; t2 < 2; ++t2) {
                int dt = dtb + t2;
                const ushort* vr = vT + ((size_t)(b * NH + h) * DH + dt * 16 + lm) * SEQ + j0;
                short8 vf0 = *(const short8*)(vr + lq * 8);
                short8 vf1 = *(const short8*)(vr + 32 + lq * 8);
                short8 af0 = *(const short8*)&cc[(tr * 16 + lm) * 72 + lq * 8];
                short8 af1 = *(const short8*)&cc[(tr * 16 + lm) * 72 + 32 + lq * 8];
                occ[t2] = MFMA(af0, vf0, occ[t2], 0, 0, 0);
                occ[t2] = MFMA(af1, vf1, occ[t2], 0, 0, 0);
            }
        }
        // no barrier: next iter's (1) protects cc (other buffer) and dqs/dks
    }

    {
        int tr = w >> 1, dtb = (w & 1) * 2;
#pragma unroll
        for (int t2 = 0; t2 < 2; ++t2) {
#pragma unroll
            for (int r = 0; r < 4; ++r) {
                int row = tr * 16 + lq * 4 + r;
                float ov = occ[t2][r] / rowsum[row];
                aob[(size_t)(b * SEQ + i0 + row) * DIM + h * DH + (dtb + t2) * 16 + lm] = f2bf(ov);
            }
        }
    }
}

extern "C" void kernel_launch(void* const* d_in, const int* in_sizes, int n_in,
                              void* d_out, int out_size, void* d_ws, size_t ws_size,
                              hipStream_t stream) {
    const float* x   = (const float*)d_in[0];
    const float* rpe = (const float*)d_in[1];
    const float* Wq  = (const float*)d_in[2];
    const float* bq  = (const float*)d_in[3];
    const float* Wk  = (const float*)d_in[4];
    const float* bk  = (const float*)d_in[5];
    const float* Wv  = (const float*)d_in[6];
    const float* bv  = (const float*)d_in[7];
    const float* qbias = (const float*)d_in[8];
    const float* vbias = (const float*)d_in[9];
    const float* Wpk = (const float*)d_in[10];
    const float* Wpq = (const float*)d_in[11];
    const float* Wo  = (const float*)d_in[12];
    const float* bo  = (const float*)d_in[13];
    float* out = (float*)d_out;

    char* ws = (char*)d_ws;
    ushort* xb    = (ushort*)ws; ws += (size_t)NTOK * DIM * 2;
    ushort* qkbuf = (ushort*)ws; ws += (size_t)NTOK * QKN * 2;
    ushort* vT    = (ushort*)ws; ws += (size_t)NTOK * DIM * 2;
    ushort* aob   = (ushort*)ws; ws += (size_t)NTOK * DIM * 2;
    ushort* rpeb  = (ushort*)ws; ws += (size_t)NPOS * DIM * 2;
    ushort* posKQ = (ushort*)ws; ws += (size_t)NPOS * PN * 2;
    ushort* wsT   = (ushort*)ws; ws += (size_t)6 * DIM * DIM * 2;   // must follow posKQ (t=767 overread pad)

    // 1) converts + weight transposes
    prep<<<dim3(12, 12, 7), dim3(256), 0, stream>>>(
        Wq, Wk, Wv, Wpk, Wpq, Wo, x, rpe, wsT, xb, rpeb);
    // 2) QKV projection + positional projections in one launch (504 blocks)
    proj_all<<<dim3(504), dim3(256), 0, stream>>>(
        xb, rpeb, wsT, bq, qbias, bk, bv, vbias, qkbuf, vT, posKQ);
    // 3) fused attention v9 (44.25KB LDS -> 3 blocks/CU, single-round grid)
    attn_fused9<<<dim3(SEQ / 64, NH, BATCH), dim3(512), 0, stream>>>(qkbuf, vT, posKQ, aob);
    // 4) output projection -> fp32 d_out (288 blocks)
    gemm128x64<<<dim3(DIM / 64, NTOK / 128), dim3(256), 0, stream>>>(
        aob, wsT + (size_t)5 * DIM * DIM, bo, out, NTOK, DIM, DIM);
}

// Round 2
// 251.665 us; speedup vs baseline: 1.2096x; 1.2096x over previous
//
#include <hip/hip_runtime.h>
#include <hip/hip_bf16.h>
#include <math.h>

#define BATCH 8
#define SEQ 384
#define DIM 768
#define NH 12
#define DH 64
#define NPOS 767
#define POS_OFF 128
#define NTOK (BATCH * SEQ)
#define QKN 1536
#define QKVN 2304
#define PN 1536

typedef __attribute__((ext_vector_type(8))) short short8;
typedef __attribute__((ext_vector_type(4))) float floatx4;
typedef unsigned int u32;

__device__ __forceinline__ ushort f2bf(float f) {
    __hip_bfloat16 h = __float2bfloat16(f);
    return *reinterpret_cast<ushort*>(&h);
}
__device__ __forceinline__ float bf2f(ushort u) {
    u32 x = ((u32)u) << 16;
    float f; __builtin_memcpy(&f, &x, 4); return f;
}

// async global->LDS, 16B per lane; lds dest = wave-uniform base + lane*16
__device__ __forceinline__ void gld16(const ushort* g, ushort* l) {
    __builtin_amdgcn_global_load_lds(
        (const __attribute__((address_space(1))) u32*)g,
        (__attribute__((address_space(3))) u32*)l, 16, 0, 0);
}

#define MFMA __builtin_amdgcn_mfma_f32_16x16x32_bf16

// ---------- prep: weight transposes (z<6) + row converts (z==6) -----------
__global__ __launch_bounds__(256) void prep(
    const float* W0, const float* W1, const float* W2,
    const float* W3, const float* W4, const float* W5,
    const float* x, const float* rpe,
    ushort* __restrict__ wsT, ushort* __restrict__ xb, ushort* __restrict__ rpeb)
{
    const int tid = threadIdx.x;
    if (blockIdx.z < 6) {
        __shared__ float t[64][65];
        const float* srcs[6] = {W0, W1, W2, W3, W4, W5};
        const float* in = srcs[blockIdx.z];
        ushort* out = wsT + (size_t)blockIdx.z * DIM * DIM;
        const int r0 = blockIdx.y * 64, c0 = blockIdx.x * 64;
        for (int p = 0; p < 16; ++p) {
            int e = tid + p * 256, i = e >> 6, j = e & 63;
            t[i][j] = in[(size_t)(r0 + i) * DIM + c0 + j];
        }
        __syncthreads();
        for (int p = 0; p < 16; ++p) {
            int e = tid + p * 256, i = e >> 6, j = e & 63;
            out[(size_t)(c0 + i) * DIM + r0 + j] = f2bf(t[j][i]);
        }
    } else {
        const int n4x = NTOK * DIM / 4;
        const int n4p = NPOS * DIM / 4;
        const int fb = blockIdx.y * 12 + blockIdx.x;      // 0..143
        for (int idx = fb * 256 + tid; idx < n4x + n4p; idx += 144 * 256) {
            const float* src; ushort* dst; int j;
            if (idx < n4x) { src = x; dst = xb; j = idx; }
            else { src = rpe + (size_t)POS_OFF * DIM; dst = rpeb; j = idx - n4x; }
            float4 f = ((const float4*)src)[j];
            ushort o[4] = {f2bf(f.x), f2bf(f.y), f2bf(f.z), f2bf(f.w)};
            *(uint2*)&dst[(size_t)j * 4] = *(uint2*)o;
        }
    }
}

// ---------- combined projections: QKV (blocks 0..431) + pos (432..503) ----
__global__ __launch_bounds__(256) void proj_all(
    const ushort* __restrict__ xb, const ushort* __restrict__ rpeb,
    const ushort* __restrict__ wsT,
    const float* __restrict__ bq, const float* __restrict__ qbias,
    const float* __restrict__ bk, const float* __restrict__ bv,
    const float* __restrict__ vbias,
    ushort* __restrict__ qk, ushort* __restrict__ vT, ushort* __restrict__ posKQ)
{
    __shared__ ushort As[128 * 64];
    __shared__ ushort Bs[128 * 64];
    const int tid = threadIdx.x;
    const int lane = tid & 63, w = tid >> 6;
    const int id = blockIdx.x;
    const bool qkvP = id < 432;
    const ushort* A; const ushort* Bt; int m0, n0, M;
    if (qkvP) {
        m0 = (id % 24) * 128; n0 = (id / 24) * 128;
        A = xb; Bt = wsT; M = NTOK;
    } else {
        int p = id - 432;
        m0 = (p % 6) * 128; n0 = (p / 6) * 128;
        A = rpeb; Bt = wsT + (size_t)3 * DIM * DIM; M = NPOS;
    }
    const int lr = lane >> 3;
    const int lc = (lane & 7) ^ (lr & 7);
    const ushort* ga[4]; const ushort* gb[4];
#pragma unroll
    for (int p = 0; p < 4; ++p) {
        int row = (w * 4 + p) * 8 + lr;
        int arow = m0 + row; if (arow > M - 1) arow = M - 1;
        ga[p] = A + (size_t)arow * DIM + lc * 8;
        gb[p] = Bt + (size_t)(n0 + row) * DIM + lc * 8;
    }
    floatx4 acc[4][4] = {};
    const int qr = (w >> 1) * 64, qc = (w & 1) * 64;
    const int lm = lane & 15, lk = lane >> 4;
    for (int k0 = 0; k0 < DIM; k0 += 64) {
#pragma unroll
        for (int p = 0; p < 4; ++p) {
            gld16(ga[p], As + (w * 4 + p) * 512);
            gld16(gb[p], Bs + (w * 4 + p) * 512);
            ga[p] += 64; gb[p] += 64;
        }
        __syncthreads();
#pragma unroll
        for (int kk = 0; kk < 2; ++kk) {
            int ch = (kk * 4 + lk) ^ (lm & 7);
            short8 af[4], bf[4];
#pragma unroll
            for (int t = 0; t < 4; ++t) {
                af[t] = *(const short8*)&As[(qr + t * 16 + lm) * 64 + ch * 8];
                bf[t] = *(const short8*)&Bs[(qc + t * 16 + lm) * 64 + ch * 8];
            }
#pragma unroll
            for (int i = 0; i < 4; ++i)
#pragma unroll
                for (int j = 0; j < 4; ++j)
                    acc[i][j] = MFMA(af[i], bf[j], acc[i][j], 0, 0, 0);
        }
        __syncthreads();
    }
    if (qkvP) {
#pragma unroll
        for (int i = 0; i < 4; ++i) {
            int mbase = m0 + qr + i * 16 + (lane >> 4) * 4;
            int bb = mbase / SEQ;
            int s0 = mbase - bb * SEQ;
#pragma unroll
            for (int j = 0; j < 4; ++j) {
                int n = n0 + qc + j * 16 + lm;
                float bs;
                if (n < 768) bs = bq[n] + qbias[n];
                else if (n < QKN) bs = bk[n - 768];
                else bs = bv[n - QKN] + vbias[n - QKN];
                if (n < QKN) {
#pragma unroll
                    for (int r = 0; r < 4; ++r)
                        qk[(size_t)(mbase + r) * QKN + n] = f2bf(acc[i][j][r] + bs);
                } else {
                    int c = n - QKN, h = c >> 6, d = c & 63;
                    ushort tmp[4];
#pragma unroll
                    for (int r = 0; r < 4; ++r) tmp[r] = f2bf(acc[i][j][r] + bs);
                    *(uint2*)&vT[(((size_t)bb * NH + h) * DH + d) * SEQ + s0] = *(uint2*)tmp;
                }
            }
        }
    } else {
#pragma unroll
        for (int i = 0; i < 4; ++i) {
            int mbase = m0 + qr + i * 16 + (lane >> 4) * 4;
#pragma unroll
            for (int j = 0; j < 4; ++j) {
                int n = n0 + qc + j * 16 + lm;
#pragma unroll
                for (int r = 0; r < 4; ++r) {
                    int row = mbase + r;
                    if (row < NPOS)
                        posKQ[(size_t)row * PN + n] = f2bf(acc[i][j][r]);
                }
            }
        }
    }
}

// ---------- 128x64-tile MFMA GEMM (output projection, 288 blocks) ---------
__global__ __launch_bounds__(256) void gemm128x64(
    const ushort* __restrict__ A, const ushort* __restrict__ Bt,
    const float* __restrict__ bias, float* __restrict__ outF,
    int M, int N, int K)
{
    __shared__ ushort As[128 * 64];
    __shared__ ushort Bs[64 * 64];
    const int tid = threadIdx.x;
    const int lane = tid & 63, w = tid >> 6;
    const int n0 = blockIdx.x * 64, m0 = blockIdx.y * 128;
    const int lr = lane >> 3;
    const int lc = (lane & 7) ^ (lr & 7);
    const ushort* ga[4]; const ushort* gb[2];
#pragma unroll
    for (int p = 0; p < 4; ++p) {
        int arow = m0 + (w * 4 + p) * 8 + lr; if (arow > M - 1) arow = M - 1;
        ga[p] = A + (size_t)arow * K + lc * 8;
    }
#pragma unroll
    for (int p = 0; p < 2; ++p)
        gb[p] = Bt + (size_t)(n0 + (w * 2 + p) * 8 + lr) * K + lc * 8;
    floatx4 acc[4][2] = {};
    const int qr = (w >> 1) * 64, qc = (w & 1) * 32;
    const int lm = lane & 15, lk = lane >> 4;
    for (int k0 = 0; k0 < K; k0 += 64) {
#pragma unroll
        for (int p = 0; p < 4; ++p) { gld16(ga[p], As + (w * 4 + p) * 512); ga[p] += 64; }
#pragma unroll
        for (int p = 0; p < 2; ++p) { gld16(gb[p], Bs + (w * 2 + p) * 512); gb[p] += 64; }
        __syncthreads();
#pragma unroll
        for (int kk = 0; kk < 2; ++kk) {
            int ch = (kk * 4 + lk) ^ (lm & 7);
            short8 af[4], bf[2];
#pragma unroll
            for (int t = 0; t < 4; ++t)
                af[t] = *(const short8*)&As[(qr + t * 16 + lm) * 64 + ch * 8];
#pragma unroll
            for (int t = 0; t < 2; ++t)
                bf[t] = *(const short8*)&Bs[(qc + t * 16 + lm) * 64 + ch * 8];
#pragma unroll
            for (int i = 0; i < 4; ++i)
#pragma unroll
                for (int j = 0; j < 2; ++j)
                    acc[i][j] = MFMA(af[i], bf[j], acc[i][j], 0, 0, 0);
        }
        __syncthreads();
    }
#pragma unroll
    for (int i = 0; i < 4; ++i) {
        int mbase = m0 + qr + i * 16 + (lane >> 4) * 4;
#pragma unroll
        for (int j = 0; j < 2; ++j) {
            int n = n0 + qc + j * 16 + lm;
            float bs = bias[n];
#pragma unroll
            for (int r = 0; r < 4; ++r) {
                int row = mbase + r;
                if (row < M) outF[(size_t)row * N + n] = acc[i][j][r] + bs;
            }
        }
    }
}

// ---------- fused attention v10: JIT global pos fragments, no spill -------
// grid (6, 12, 8), 512 threads (8 waves). LDS 44.25KB -> 3 blocks/CU
// (capacity 768 >= 576: single-round makespan). posKQ (2.3MB) is L2-hot;
// dq B-frags / dk A-frag load straight to registers JUST-IN-TIME inside
// phase B (per-kk, 16-32B live range) so the register allocator never has
// to hold them across a barrier -- v9 held 40 VGPRs of fragments live
// through phase B under an 80-VGPR cap and spilled 160MB/iter to scratch.
// t=767 overread (i0=0, jt=5) lands in wsT pad; outputs band-masked.
__global__ __launch_bounds__(512, 6) void attn_fused10(
    const ushort* __restrict__ qk, const ushort* __restrict__ vT,
    const ushort* __restrict__ posKQ, ushort* __restrict__ aob)
{
    __shared__ ushort kt[64 * 64];        // 8 KB  k tile (swizzled)
    __shared__ ushort ccpt[2][64 * 72];   // 18 KB c2c scores / P (in-place), dbuf
    __shared__ ushort dqs[64 * 72];       // 9 KB  dq pre-shifted: [i][j]=dq[i][j-i+63]
    __shared__ ushort dks[64 * 72];       // 9 KB  dk pre-shifted: [i][j]=dk[j-i+63][j]
    __shared__ float rowsum[64];

    const int tid = threadIdx.x;
    const int lane = tid & 63, w = tid >> 6;
    const int i0 = blockIdx.x * 64;
    const int h = blockIdx.y, b = blockIdx.z;
    const int lm = lane & 15, lq = lane >> 4;
    const int lr = lane >> 3, l8 = lane & 7;
    const int lc = l8 ^ (lr & 7);                 // swizzled source chunk
    const int exr = tid >> 3, exseg = tid & 7;    // 64 rows x 8 segs (phase C)

    if (tid < 64) rowsum[tid] = 0.f;

    // q fragments: register-resident (i-tile w>>1; two waves share a tile)
    short8 qf[2];
    {
        const ushort* qr = qk + (size_t)(b * SEQ + i0 + (w >> 1) * 16 + lm) * QKN + h * DH;
        qf[0] = *(const short8*)(qr + lq * 8);
        qf[1] = *(const short8*)(qr + 32 + lq * 8);
    }
    const ushort* kb = qk + 768 + h * DH;
    floatx4 occ[2] = {};

    // per-thread global fragment pointers into posKQ (advance 64*PN per jt)
    const int t0i = 0 - i0 + 320;
    const int tcb = (w & 1) * 4;
    const ushort* kp_p[4];
#pragma unroll
    for (int s = 0; s < 4; ++s)
        kp_p[s] = posKQ + (size_t)(t0i + (tcb + s) * 16 + lm) * PN + h * DH + lq * 8;
    const ushort* qp_p = posKQ + (size_t)(t0i + w * 16 + lm) * PN + 768 + h * DH + lq * 8;

    // stage j-tile 0 (k only)
    gld16(kb + (size_t)(b * SEQ + 8 * w + lr) * QKN + lc * 8, kt + w * 512);

    for (int jt = 0; jt < 6; ++jt) {
        const int j0 = jt * 64;
        ushort* cc = ccpt[jt & 1];

        __syncthreads();        // (1) kt staged; prev C (dqs/dks) + PV (other cc) done

        // ---- phase B: c2c + dq + dk -> bf16 buffers, unique writers ----
        { // c2c: i-tile w>>1 x j-tiles (w&1)*2+{0,1}
            int tr = w >> 1, tjb = (w & 1) * 2;
            floatx4 a[2] = {};
#pragma unroll
            for (int kk = 0; kk < 2; ++kk) {
                int ch = (kk * 4 + lq) ^ (lm & 7);
                short8 b0 = *(const short8*)&kt[(tjb * 16 + lm) * 64 + ch * 8];
                short8 b1 = *(const short8*)&kt[((tjb + 1) * 16 + lm) * 64 + ch * 8];
                a[0] = MFMA(qf[kk], b0, a[0], 0, 0, 0);
                a[1] = MFMA(qf[kk], b1, a[1], 0, 0, 0);
            }
#pragma unroll
            for (int s = 0; s < 2; ++s) {
                int j = (tjb + s) * 16 + lm;
#pragma unroll
                for (int r = 0; r < 4; ++r)
                    cc[(tr * 16 + lq * 4 + r) * 72 + j] = f2bf(a[s][r]);
            }
        }
        { // dq: i-tile w>>1 x t-tiles (w&1)*4+{0..3}; Kp frags JIT from L2
            int tr = w >> 1;
            floatx4 d[4] = {};
#pragma unroll
            for (int kk = 0; kk < 2; ++kk) {
                short8 kpf[4];
#pragma unroll
                for (int s = 0; s < 4; ++s)
                    kpf[s] = *(const short8*)(kp_p[s] + kk * 32);
#pragma unroll
                for (int s = 0; s < 4; ++s)
                    d[s] = MFMA(qf[kk], kpf[s], d[s], 0, 0, 0);
            }
#pragma unroll
            for (int s = 0; s < 4; ++s) {
                int t = (tcb + s) * 16 + lm;
#pragma unroll
                for (int r = 0; r < 4; ++r) {
                    int i = tr * 16 + lq * 4 + r;
                    int j = t + i - 63;
                    if ((unsigned)j < 64u) dqs[i * 72 + j] = f2bf(d[s][r]);
                }
            }
        }
        { // dk: t-tile w x j-tiles {0..3}; Qp frag JIT from L2
            floatx4 e[4] = {};
#pragma unroll
            for (int kk = 0; kk < 2; ++kk) {
                short8 qpf = *(const short8*)(qp_p + kk * 32);
                int ch = (kk * 4 + lq) ^ (lm & 7);
#pragma unroll
                for (int s = 0; s < 4; ++s) {
                    short8 bf = *(const short8*)&kt[(s * 16 + lm) * 64 + ch * 8];
                    e[s] = MFMA(qpf, bf, e[s], 0, 0, 0);
                }
            }
#pragma unroll
            for (int s = 0; s < 4; ++s) {
                int j = s * 16 + lm;
#pragma unroll
                for (int r = 0; r < 4; ++r) {
                    int t = w * 16 + lq * 4 + r;
                    int i = j - t + 63;
                    if ((unsigned)i < 64u) dks[i * 72 + j] = f2bf(e[s][r]);
                }
            }
        }
        __syncthreads();        // (2) B done; kt free

        // issue next iter's k staging (overlaps phases C and D)
        if (jt < 5) {
            gld16(kb + (size_t)(b * SEQ + j0 + 64 + 8 * w + lr) * QKN + lc * 8, kt + w * 512);
        }
        // advance pos fragment pointers
#pragma unroll
        for (int s = 0; s < 4; ++s) kp_p[s] += 64 * PN;
        qp_p += 64 * PN;

        // ---- phase C: gather 3 terms (b128), exp, rowsum, P in place ----
        {
            int off = exr * 72 + exseg * 8;
            uint4 c4 = *(const uint4*)&cc[off];
            uint4 q4 = *(const uint4*)&dqs[off];
            uint4 k4 = *(const uint4*)&dks[off];
            const ushort* cu = (const ushort*)&c4;
            const ushort* qu = (const ushort*)&q4;
            const ushort* ku = (const ushort*)&k4;
            float psum = 0.f;
            ushort pv[8];
#pragma unroll
            for (int c = 0; c < 8; ++c) {
                float sv = (bf2f(cu[c]) + bf2f(qu[c]) + bf2f(ku[c])) * 0.125f;
                float pe = __expf(sv);
                psum += pe;
                pv[c] = f2bf(pe);
            }
            psum += __shfl_xor(psum, 1);
            psum += __shfl_xor(psum, 2);
            psum += __shfl_xor(psum, 4);
            if (exseg == 0) rowsum[exr] += psum;
            *(uint4*)&cc[off] = *(uint4*)pv;
        }
        __syncthreads();        // (3) P visible

        // ---- phase D: PV accumulate; v direct-to-register -------------
        {
            int tr = w >> 1, dtb = (w & 1) * 2;
#pragma unroll
            for (int t2 = 0; t2 < 2; ++t2) {
                int dt = dtb + t2;
                const ushort* vr = vT + ((size_t)(b * NH + h) * DH + dt * 16 + lm) * SEQ + j0;
                short8 vf0 = *(const short8*)(vr + lq * 8);
                short8 vf1 = *(const short8*)(vr + 32 + lq * 8);
                short8 af0 = *(const short8*)&cc[(tr * 16 + lm) * 72 + lq * 8];
                short8 af1 = *(const short8*)&cc[(tr * 16 + lm) * 72 + 32 + lq * 8];
                occ[t2] = MFMA(af0, vf0, occ[t2], 0, 0, 0);
                occ[t2] = MFMA(af1, vf1, occ[t2], 0, 0, 0);
            }
        }
        // no barrier: next iter's (1) protects cc (other buffer) and dqs/dks
    }

    {
        int tr = w >> 1, dtb = (w & 1) * 2;
#pragma unroll
        for (int t2 = 0; t2 < 2; ++t2) {
#pragma unroll
            for (int r = 0; r < 4; ++r) {
                int row = tr * 16 + lq * 4 + r;
                float ov = occ[t2][r] / rowsum[row];
                aob[(size_t)(b * SEQ + i0 + row) * DIM + h * DH + (dtb + t2) * 16 + lm] = f2bf(ov);
            }
        }
    }
}

extern "C" void kernel_launch(void* const* d_in, const int* in_sizes, int n_in,
                              void* d_out, int out_size, void* d_ws, size_t ws_size,
                              hipStream_t stream) {
    const float* x   = (const float*)d_in[0];
    const float* rpe = (const float*)d_in[1];
    const float* Wq  = (const float*)d_in[2];
    const float* bq  = (const float*)d_in[3];
    const float* Wk  = (const float*)d_in[4];
    const float* bk  = (const float*)d_in[5];
    const float* Wv  = (const float*)d_in[6];
    const float* bv  = (const float*)d_in[7];
    const float* qbias = (const float*)d_in[8];
    const float* vbias = (const float*)d_in[9];
    const float* Wpk = (const float*)d_in[10];
    const float* Wpq = (const float*)d_in[11];
    const float* Wo  = (const float*)d_in[12];
    const float* bo  = (const float*)d_in[13];
    float* out = (float*)d_out;

    char* ws = (char*)d_ws;
    ushort* xb    = (ushort*)ws; ws += (size_t)NTOK * DIM * 2;
    ushort* qkbuf = (ushort*)ws; ws += (size_t)NTOK * QKN * 2;
    ushort* vT    = (ushort*)ws; ws += (size_t)NTOK * DIM * 2;
    ushort* aob   = (ushort*)ws; ws += (size_t)NTOK * DIM * 2;
    ushort* rpeb  = (ushort*)ws; ws += (size_t)NPOS * DIM * 2;
    ushort* posKQ = (ushort*)ws; ws += (size_t)NPOS * PN * 2;
    ushort* wsT   = (ushort*)ws; ws += (size_t)6 * DIM * DIM * 2;   // must follow posKQ (t=767 overread pad)

    // 1) converts + weight transposes
    prep<<<dim3(12, 12, 7), dim3(256), 0, stream>>>(
        Wq, Wk, Wv, Wpk, Wpq, Wo, x, rpe, wsT, xb, rpeb);
    // 2) QKV projection + positional projections in one launch (504 blocks)
    proj_all<<<dim3(504), dim3(256), 0, stream>>>(
        xb, rpeb, wsT, bq, qbias, bk, bv, vbias, qkbuf, vT, posKQ);
    // 3) fused attention v10 (44.25KB LDS, 3 blocks/CU, JIT pos frags)
    attn_fused10<<<dim3(SEQ / 64, NH, BATCH), dim3(512), 0, stream>>>(qkbuf, vT, posKQ, aob);
    // 4) output projection -> fp32 d_out (288 blocks)
    gemm128x64<<<dim3(DIM / 64, NTOK / 128), dim3(256), 0, stream>>>(
        aob, wsT + (size_t)5 * DIM * DIM, bo, out, NTOK, DIM, DIM);
}

// Round 3
// 222.825 us; speedup vs baseline: 1.3662x; 1.1294x over previous
//
#include <hip/hip_runtime.h>
#include <hip/hip_bf16.h>
#include <math.h>

#define BATCH 8
#define SEQ 384
#define DIM 768
#define NH 12
#define DH 64
#define NPOS 767
#define POS_OFF 128
#define NTOK (BATCH * SEQ)
#define QKN 1536
#define QKVN 2304
#define PN 1536

typedef __attribute__((ext_vector_type(8))) short short8;
typedef __attribute__((ext_vector_type(4))) float floatx4;
typedef unsigned int u32;

__device__ __forceinline__ ushort f2bf(float f) {
    __hip_bfloat16 h = __float2bfloat16(f);
    return *reinterpret_cast<ushort*>(&h);
}
__device__ __forceinline__ float bf2f(ushort u) {
    u32 x = ((u32)u) << 16;
    float f; __builtin_memcpy(&f, &x, 4); return f;
}

// async global->LDS, 16B per lane; lds dest = wave-uniform base + lane*16
__device__ __forceinline__ void gld16(const ushort* g, ushort* l) {
    __builtin_amdgcn_global_load_lds(
        (const __attribute__((address_space(1))) u32*)g,
        (__attribute__((address_space(3))) u32*)l, 16, 0, 0);
}

#define MFMA __builtin_amdgcn_mfma_f32_16x16x32_bf16

// ---------- prep: weight transposes (z<6) + row converts (z==6) -----------
__global__ __launch_bounds__(256) void prep(
    const float* W0, const float* W1, const float* W2,
    const float* W3, const float* W4, const float* W5,
    const float* x, const float* rpe,
    ushort* __restrict__ wsT, ushort* __restrict__ xb, ushort* __restrict__ rpeb)
{
    const int tid = threadIdx.x;
    if (blockIdx.z < 6) {
        __shared__ float t[64][65];
        const float* srcs[6] = {W0, W1, W2, W3, W4, W5};
        const float* in = srcs[blockIdx.z];
        ushort* out = wsT + (size_t)blockIdx.z * DIM * DIM;
        const int r0 = blockIdx.y * 64, c0 = blockIdx.x * 64;
        for (int p = 0; p < 16; ++p) {
            int e = tid + p * 256, i = e >> 6, j = e & 63;
            t[i][j] = in[(size_t)(r0 + i) * DIM + c0 + j];
        }
        __syncthreads();
        for (int p = 0; p < 16; ++p) {
            int e = tid + p * 256, i = e >> 6, j = e & 63;
            out[(size_t)(c0 + i) * DIM + r0 + j] = f2bf(t[j][i]);
        }
    } else {
        const int n4x = NTOK * DIM / 4;
        const int n4p = NPOS * DIM / 4;
        const int fb = blockIdx.y * 12 + blockIdx.x;      // 0..143
        for (int idx = fb * 256 + tid; idx < n4x + n4p; idx += 144 * 256) {
            const float* src; ushort* dst; int j;
            if (idx < n4x) { src = x; dst = xb; j = idx; }
            else { src = rpe + (size_t)POS_OFF * DIM; dst = rpeb; j = idx - n4x; }
            float4 f = ((const float4*)src)[j];
            ushort o[4] = {f2bf(f.x), f2bf(f.y), f2bf(f.z), f2bf(f.w)};
            *(uint2*)&dst[(size_t)j * 4] = *(uint2*)o;
        }
    }
}

// ---------- combined projections: QKV (blocks 0..431) + pos (432..503) ----
__global__ __launch_bounds__(256) void proj_all(
    const ushort* __restrict__ xb, const ushort* __restrict__ rpeb,
    const ushort* __restrict__ wsT,
    const float* __restrict__ bq, const float* __restrict__ qbias,
    const float* __restrict__ bk, const float* __restrict__ bv,
    const float* __restrict__ vbias,
    ushort* __restrict__ qk, ushort* __restrict__ vT, ushort* __restrict__ posKQ)
{
    __shared__ ushort As[128 * 64];
    __shared__ ushort Bs[128 * 64];
    const int tid = threadIdx.x;
    const int lane = tid & 63, w = tid >> 6;
    const int id = blockIdx.x;
    const bool qkvP = id < 432;
    const ushort* A; const ushort* Bt; int m0, n0, M;
    if (qkvP) {
        m0 = (id % 24) * 128; n0 = (id / 24) * 128;
        A = xb; Bt = wsT; M = NTOK;
    } else {
        int p = id - 432;
        m0 = (p % 6) * 128; n0 = (p / 6) * 128;
        A = rpeb; Bt = wsT + (size_t)3 * DIM * DIM; M = NPOS;
    }
    const int lr = lane >> 3;
    const int lc = (lane & 7) ^ (lr & 7);
    const ushort* ga[4]; const ushort* gb[4];
#pragma unroll
    for (int p = 0; p < 4; ++p) {
        int row = (w * 4 + p) * 8 + lr;
        int arow = m0 + row; if (arow > M - 1) arow = M - 1;
        ga[p] = A + (size_t)arow * DIM + lc * 8;
        gb[p] = Bt + (size_t)(n0 + row) * DIM + lc * 8;
    }
    floatx4 acc[4][4] = {};
    const int qr = (w >> 1) * 64, qc = (w & 1) * 64;
    const int lm = lane & 15, lk = lane >> 4;
    for (int k0 = 0; k0 < DIM; k0 += 64) {
#pragma unroll
        for (int p = 0; p < 4; ++p) {
            gld16(ga[p], As + (w * 4 + p) * 512);
            gld16(gb[p], Bs + (w * 4 + p) * 512);
            ga[p] += 64; gb[p] += 64;
        }
        __syncthreads();
#pragma unroll
        for (int kk = 0; kk < 2; ++kk) {
            int ch = (kk * 4 + lk) ^ (lm & 7);
            short8 af[4], bf[4];
#pragma unroll
            for (int t = 0; t < 4; ++t) {
                af[t] = *(const short8*)&As[(qr + t * 16 + lm) * 64 + ch * 8];
                bf[t] = *(const short8*)&Bs[(qc + t * 16 + lm) * 64 + ch * 8];
            }
#pragma unroll
            for (int i = 0; i < 4; ++i)
#pragma unroll
                for (int j = 0; j < 4; ++j)
                    acc[i][j] = MFMA(af[i], bf[j], acc[i][j], 0, 0, 0);
        }
        __syncthreads();
    }
    if (qkvP) {
#pragma unroll
        for (int i = 0; i < 4; ++i) {
            int mbase = m0 + qr + i * 16 + (lane >> 4) * 4;
            int bb = mbase / SEQ;
            int s0 = mbase - bb * SEQ;
#pragma unroll
            for (int j = 0; j < 4; ++j) {
                int n = n0 + qc + j * 16 + lm;
                float bs;
                if (n < 768) bs = bq[n] + qbias[n];
                else if (n < QKN) bs = bk[n - 768];
                else bs = bv[n - QKN] + vbias[n - QKN];
                if (n < QKN) {
#pragma unroll
                    for (int r = 0; r < 4; ++r)
                        qk[(size_t)(mbase + r) * QKN + n] = f2bf(acc[i][j][r] + bs);
                } else {
                    int c = n - QKN, h = c >> 6, d = c & 63;
                    ushort tmp[4];
#pragma unroll
                    for (int r = 0; r < 4; ++r) tmp[r] = f2bf(acc[i][j][r] + bs);
                    *(uint2*)&vT[(((size_t)bb * NH + h) * DH + d) * SEQ + s0] = *(uint2*)tmp;
                }
            }
        }
    } else {
#pragma unroll
        for (int i = 0; i < 4; ++i) {
            int mbase = m0 + qr + i * 16 + (lane >> 4) * 4;
#pragma unroll
            for (int j = 0; j < 4; ++j) {
                int n = n0 + qc + j * 16 + lm;
#pragma unroll
                for (int r = 0; r < 4; ++r) {
                    int row = mbase + r;
                    if (row < NPOS)
                        posKQ[(size_t)row * PN + n] = f2bf(acc[i][j][r]);
                }
            }
        }
    }
}

// ---------- 128x64-tile MFMA GEMM (output projection, 288 blocks) ---------
__global__ __launch_bounds__(256) void gemm128x64(
    const ushort* __restrict__ A, const ushort* __restrict__ Bt,
    const float* __restrict__ bias, float* __restrict__ outF,
    int M, int N, int K)
{
    __shared__ ushort As[128 * 64];
    __shared__ ushort Bs[64 * 64];
    const int tid = threadIdx.x;
    const int lane = tid & 63, w = tid >> 6;
    const int n0 = blockIdx.x * 64, m0 = blockIdx.y * 128;
    const int lr = lane >> 3;
    const int lc = (lane & 7) ^ (lr & 7);
    const ushort* ga[4]; const ushort* gb[2];
#pragma unroll
    for (int p = 0; p < 4; ++p) {
        int arow = m0 + (w * 4 + p) * 8 + lr; if (arow > M - 1) arow = M - 1;
        ga[p] = A + (size_t)arow * K + lc * 8;
    }
#pragma unroll
    for (int p = 0; p < 2; ++p)
        gb[p] = Bt + (size_t)(n0 + (w * 2 + p) * 8 + lr) * K + lc * 8;
    floatx4 acc[4][2] = {};
    const int qr = (w >> 1) * 64, qc = (w & 1) * 32;
    const int lm = lane & 15, lk = lane >> 4;
    for (int k0 = 0; k0 < K; k0 += 64) {
#pragma unroll
        for (int p = 0; p < 4; ++p) { gld16(ga[p], As + (w * 4 + p) * 512); ga[p] += 64; }
#pragma unroll
        for (int p = 0; p < 2; ++p) { gld16(gb[p], Bs + (w * 2 + p) * 512); gb[p] += 64; }
        __syncthreads();
#pragma unroll
        for (int kk = 0; kk < 2; ++kk) {
            int ch = (kk * 4 + lk) ^ (lm & 7);
            short8 af[4], bf[2];
#pragma unroll
            for (int t = 0; t < 4; ++t)
                af[t] = *(const short8*)&As[(qr + t * 16 + lm) * 64 + ch * 8];
#pragma unroll
            for (int t = 0; t < 2; ++t)
                bf[t] = *(const short8*)&Bs[(qc + t * 16 + lm) * 64 + ch * 8];
#pragma unroll
            for (int i = 0; i < 4; ++i)
#pragma unroll
                for (int j = 0; j < 2; ++j)
                    acc[i][j] = MFMA(af[i], bf[j], acc[i][j], 0, 0, 0);
        }
        __syncthreads();
    }
#pragma unroll
    for (int i = 0; i < 4; ++i) {
        int mbase = m0 + qr + i * 16 + (lane >> 4) * 4;
#pragma unroll
        for (int j = 0; j < 2; ++j) {
            int n = n0 + qc + j * 16 + lm;
            float bs = bias[n];
#pragma unroll
            for (int r = 0; r < 4; ++r) {
                int row = mbase + r;
                if (row < M) outF[(size_t)row * N + n] = acc[i][j][r] + bs;
            }
        }
    }
}

// ---------- fused attention v11: register-liveness-engineered, no spill ---
// grid (6, 12, 8), 512 threads (8 waves). LDS 44.25KB -> 3 blocks/CU
// (capacity 768 >= 576: single-round makespan). (512,6) caps regs at ~80;
// v9/v10 spilled because phase B's hoisted fragment loads + accumulators
// exceeded it. v11: (a) persistent state trimmed to 2 base pointers
// (tcb pre-folded) + staging ptr; (b) dq/dk computed in 2-tile halves
// (peak transient = 16 frag + 8 acc regs); (c) sched_barrier(0) fences
// stop the scheduler re-merging phases. t=767 overread lands in wsT pad.
__global__ __launch_bounds__(512, 6) void attn_fused11(
    const ushort* __restrict__ qk, const ushort* __restrict__ vT,
    const ushort* __restrict__ posKQ, ushort* __restrict__ aob)
{
    __shared__ ushort kt[64 * 64];        // 8 KB  k tile (swizzled)
    __shared__ ushort ccpt[2][64 * 72];   // 18 KB c2c scores / P (in-place), dbuf
    __shared__ ushort dqs[64 * 72];       // 9 KB  dq pre-shifted: [i][j]=dq[i][j-i+63]
    __shared__ ushort dks[64 * 72];       // 9 KB  dk pre-shifted: [i][j]=dk[j-i+63][j]
    __shared__ float rowsum[64];

    const int tid = threadIdx.x;
    const int lane = tid & 63, w = tid >> 6;
    const int i0 = blockIdx.x * 64;
    const int h = blockIdx.y, b = blockIdx.z;
    const int lm = lane & 15, lq = lane >> 4;
    const int lr = lane >> 3, l8 = lane & 7;
    const int lc = l8 ^ (lr & 7);                 // swizzled source chunk
    const int exr = tid >> 3, exseg = tid & 7;    // 64 rows x 8 segs (phase C)

    if (tid < 64) rowsum[tid] = 0.f;

    // q fragments: register-resident (i-tile w>>1; two waves share a tile)
    short8 qf[2];
    {
        const ushort* qr = qk + (size_t)(b * SEQ + i0 + (w >> 1) * 16 + lm) * QKN + h * DH;
        qf[0] = *(const short8*)(qr + lq * 8);
        qf[1] = *(const short8*)(qr + 32 + lq * 8);
    }
    floatx4 occ[2] = {};

    // persistent pointers (advance per jt): dq Kp base (tcb folded in),
    // dk Qp base, k staging base
    const int t0i = 320 - i0;
    const int tcb = (w & 1) * 4;
    const ushort* dq_p = posKQ + (size_t)(t0i + tcb * 16 + lm) * PN + h * DH + lq * 8;
    const ushort* qp_p = posKQ + (size_t)(t0i + w * 16 + lm) * PN + 768 + h * DH + lq * 8;
    const ushort* kst = qk + 768 + h * DH + (size_t)(b * SEQ + 8 * w + lr) * QKN + lc * 8;

    // stage j-tile 0 (k only)
    gld16(kst, kt + w * 512);
    kst += (size_t)64 * QKN;

    for (int jt = 0; jt < 6; ++jt) {
        const int j0 = jt * 64;
        ushort* cc = ccpt[jt & 1];

        __syncthreads();        // (1) kt staged; prev C (dqs/dks) + PV (other cc) done

        // ---- phase B: c2c + dq + dk -> bf16 buffers, unique writers ----
        { // c2c: i-tile w>>1 x j-tiles (w&1)*2+{0,1}
            int tr = w >> 1, tjb = (w & 1) * 2;
            floatx4 a0 = {}, a1 = {};
#pragma unroll
            for (int kk = 0; kk < 2; ++kk) {
                int ch = (kk * 4 + lq) ^ (lm & 7);
                short8 b0 = *(const short8*)&kt[(tjb * 16 + lm) * 64 + ch * 8];
                short8 b1 = *(const short8*)&kt[((tjb + 1) * 16 + lm) * 64 + ch * 8];
                a0 = MFMA(qf[kk], b0, a0, 0, 0, 0);
                a1 = MFMA(qf[kk], b1, a1, 0, 0, 0);
            }
#pragma unroll
            for (int r = 0; r < 4; ++r) {
                cc[(tr * 16 + lq * 4 + r) * 72 + tjb * 16 + lm] = f2bf(a0[r]);
                cc[(tr * 16 + lq * 4 + r) * 72 + (tjb + 1) * 16 + lm] = f2bf(a1[r]);
            }
        }
        __builtin_amdgcn_sched_barrier(0);
        { // dq: i-tile w>>1 x t-tiles (tcb+{0..3}); 2-tile halves, JIT L2 loads
            int tr = w >> 1;
#pragma unroll
            for (int hf = 0; hf < 2; ++hf) {
                floatx4 d0 = {}, d1 = {};
#pragma unroll
                for (int kk = 0; kk < 2; ++kk) {
                    short8 k0 = *(const short8*)(dq_p + (size_t)(hf * 2 + 0) * 16 * PN + kk * 32);
                    short8 k1 = *(const short8*)(dq_p + (size_t)(hf * 2 + 1) * 16 * PN + kk * 32);
                    d0 = MFMA(qf[kk], k0, d0, 0, 0, 0);
                    d1 = MFMA(qf[kk], k1, d1, 0, 0, 0);
                }
#pragma unroll
                for (int s = 0; s < 2; ++s) {
                    int t = (tcb + hf * 2 + s) * 16 + lm;
#pragma unroll
                    for (int r = 0; r < 4; ++r) {
                        int i = tr * 16 + lq * 4 + r;
                        int j = t + i - 63;
                        float dv = s ? d1[r] : d0[r];
                        if ((unsigned)j < 64u) dqs[i * 72 + j] = f2bf(dv);
                    }
                }
                __builtin_amdgcn_sched_barrier(0);
            }
        }
        { // dk: t-tile w x j-tiles {0..3}; 2-tile halves, Qp JIT from L2
#pragma unroll
            for (int hf = 0; hf < 2; ++hf) {
                floatx4 e0 = {}, e1 = {};
#pragma unroll
                for (int kk = 0; kk < 2; ++kk) {
                    short8 qpf = *(const short8*)(qp_p + kk * 32);
                    int ch = (kk * 4 + lq) ^ (lm & 7);
                    short8 b0 = *(const short8*)&kt[((hf * 2 + 0) * 16 + lm) * 64 + ch * 8];
                    short8 b1 = *(const short8*)&kt[((hf * 2 + 1) * 16 + lm) * 64 + ch * 8];
                    e0 = MFMA(qpf, b0, e0, 0, 0, 0);
                    e1 = MFMA(qpf, b1, e1, 0, 0, 0);
                }
#pragma unroll
                for (int s = 0; s < 2; ++s) {
                    int j = (hf * 2 + s) * 16 + lm;
#pragma unroll
                    for (int r = 0; r < 4; ++r) {
                        int t = w * 16 + lq * 4 + r;
                        int i = j - t + 63;
                        float ev = s ? e1[r] : e0[r];
                        if ((unsigned)i < 64u) dks[i * 72 + j] = f2bf(ev);
                    }
                }
                __builtin_amdgcn_sched_barrier(0);
            }
        }
        __syncthreads();        // (2) B done; kt free

        // issue next iter's k staging (overlaps phases C and D)
        if (jt < 5) {
            gld16(kst, kt + w * 512);
            kst += (size_t)64 * QKN;
        }
        dq_p += (size_t)64 * PN;
        qp_p += (size_t)64 * PN;

        // ---- phase C: gather 3 terms (b128), exp, rowsum, P in place ----
        {
            int off = exr * 72 + exseg * 8;
            uint4 c4 = *(const uint4*)&cc[off];
            uint4 q4 = *(const uint4*)&dqs[off];
            uint4 k4 = *(const uint4*)&dks[off];
            const ushort* cu = (const ushort*)&c4;
            const ushort* qu = (const ushort*)&q4;
            const ushort* ku = (const ushort*)&k4;
            float psum = 0.f;
            ushort pv[8];
#pragma unroll
            for (int c = 0; c < 8; ++c) {
                float sv = (bf2f(cu[c]) + bf2f(qu[c]) + bf2f(ku[c])) * 0.125f;
                float pe = __expf(sv);
                psum += pe;
                pv[c] = f2bf(pe);
            }
            psum += __shfl_xor(psum, 1);
            psum += __shfl_xor(psum, 2);
            psum += __shfl_xor(psum, 4);
            if (exseg == 0) rowsum[exr] += psum;
            *(uint4*)&cc[off] = *(uint4*)pv;
        }
        __syncthreads();        // (3) P visible

        // ---- phase D: PV accumulate; v direct-to-register -------------
        {
            int tr = w >> 1, dtb = (w & 1) * 2;
#pragma unroll
            for (int t2 = 0; t2 < 2; ++t2) {
                int dt = dtb + t2;
                const ushort* vr = vT + ((size_t)(b * NH + h) * DH + dt * 16 + lm) * SEQ + j0;
                short8 vf0 = *(const short8*)(vr + lq * 8);
                short8 vf1 = *(const short8*)(vr + 32 + lq * 8);
                short8 af0 = *(const short8*)&cc[(tr * 16 + lm) * 72 + lq * 8];
                short8 af1 = *(const short8*)&cc[(tr * 16 + lm) * 72 + 32 + lq * 8];
                occ[t2] = MFMA(af0, vf0, occ[t2], 0, 0, 0);
                occ[t2] = MFMA(af1, vf1, occ[t2], 0, 0, 0);
            }
        }
        // no barrier: next iter's (1) protects cc (other buffer) and dqs/dks
    }

    {
        int tr = w >> 1, dtb = (w & 1) * 2;
#pragma unroll
        for (int t2 = 0; t2 < 2; ++t2) {
#pragma unroll
            for (int r = 0; r < 4; ++r) {
                int row = tr * 16 + lq * 4 + r;
                float ov = occ[t2][r] / rowsum[row];
                aob[(size_t)(b * SEQ + i0 + row) * DIM + h * DH + (dtb + t2) * 16 + lm] = f2bf(ov);
            }
        }
    }
}

extern "C" void kernel_launch(void* const* d_in, const int* in_sizes, int n_in,
                              void* d_out, int out_size, void* d_ws, size_t ws_size,
                              hipStream_t stream) {
    const float* x   = (const float*)d_in[0];
    const float* rpe = (const float*)d_in[1];
    const float* Wq  = (const float*)d_in[2];
    const float* bq  = (const float*)d_in[3];
    const float* Wk  = (const float*)d_in[4];
    const float* bk  = (const float*)d_in[5];
    const float* Wv  = (const float*)d_in[6];
    const float* bv  = (const float*)d_in[7];
    const float* qbias = (const float*)d_in[8];
    const float* vbias = (const float*)d_in[9];
    const float* Wpk = (const float*)d_in[10];
    const float* Wpq = (const float*)d_in[11];
    const float* Wo  = (const float*)d_in[12];
    const float* bo  = (const float*)d_in[13];
    float* out = (float*)d_out;

    char* ws = (char*)d_ws;
    ushort* xb    = (ushort*)ws; ws += (size_t)NTOK * DIM * 2;
    ushort* qkbuf = (ushort*)ws; ws += (size_t)NTOK * QKN * 2;
    ushort* vT    = (ushort*)ws; ws += (size_t)NTOK * DIM * 2;
    ushort* aob   = (ushort*)ws; ws += (size_t)NTOK * DIM * 2;
    ushort* rpeb  = (ushort*)ws; ws += (size_t)NPOS * DIM * 2;
    ushort* posKQ = (ushort*)ws; ws += (size_t)NPOS * PN * 2;
    ushort* wsT   = (ushort*)ws; ws += (size_t)6 * DIM * DIM * 2;   // must follow posKQ (t=767 overread pad)

    // 1) converts + weight transposes
    prep<<<dim3(12, 12, 7), dim3(256), 0, stream>>>(
        Wq, Wk, Wv, Wpk, Wpq, Wo, x, rpe, wsT, xb, rpeb);
    // 2) QKV projection + positional projections in one launch (504 blocks)
    proj_all<<<dim3(504), dim3(256), 0, stream>>>(
        xb, rpeb, wsT, bq, qbias, bk, bv, vbias, qkbuf, vT, posKQ);
    // 3) fused attention v11 (44.25KB LDS, 3 blocks/CU, liveness-engineered)
    attn_fused11<<<dim3(SEQ / 64, NH, BATCH), dim3(512), 0, stream>>>(qkbuf, vT, posKQ, aob);
    // 4) output projection -> fp32 d_out (288 blocks)
    gemm128x64<<<dim3(DIM / 64, NTOK / 128), dim3(256), 0, stream>>>(
        aob, wsT + (size_t)5 * DIM * DIM, bo, out, NTOK, DIM, DIM);
}

// Round 4
// 222.013 us; speedup vs baseline: 1.3712x; 1.0037x over previous
//
#include <hip/hip_runtime.h>
#include <hip/hip_bf16.h>
#include <math.h>

#define BATCH 8
#define SEQ 384
#define DIM 768
#define NH 12
#define DH 64
#define NPOS 767
#define POS_OFF 128
#define NTOK (BATCH * SEQ)
#define QKN 1536
#define QKVN 2304
#define PN 1536

typedef __attribute__((ext_vector_type(8))) short short8;
typedef __attribute__((ext_vector_type(4))) float floatx4;
typedef unsigned int u32;

__device__ __forceinline__ ushort f2bf(float f) {
    __hip_bfloat16 h = __float2bfloat16(f);
    return *reinterpret_cast<ushort*>(&h);
}
__device__ __forceinline__ float bf2f(ushort u) {
    u32 x = ((u32)u) << 16;
    float f; __builtin_memcpy(&f, &x, 4); return f;
}

// async global->LDS, 16B per lane; lds dest = wave-uniform base + lane*16
__device__ __forceinline__ void gld16(const ushort* g, ushort* l) {
    __builtin_amdgcn_global_load_lds(
        (const __attribute__((address_space(1))) u32*)g,
        (__attribute__((address_space(3))) u32*)l, 16, 0, 0);
}

#define MFMA __builtin_amdgcn_mfma_f32_16x16x32_bf16

// ---------- prep: weight transposes (z<6) + row converts (z==6) -----------
__global__ __launch_bounds__(256) void prep(
    const float* W0, const float* W1, const float* W2,
    const float* W3, const float* W4, const float* W5,
    const float* x, const float* rpe,
    ushort* __restrict__ wsT, ushort* __restrict__ xb, ushort* __restrict__ rpeb)
{
    const int tid = threadIdx.x;
    if (blockIdx.z < 6) {
        __shared__ float t[64][65];
        const float* srcs[6] = {W0, W1, W2, W3, W4, W5};
        const float* in = srcs[blockIdx.z];
        ushort* out = wsT + (size_t)blockIdx.z * DIM * DIM;
        const int r0 = blockIdx.y * 64, c0 = blockIdx.x * 64;
        for (int p = 0; p < 16; ++p) {
            int e = tid + p * 256, i = e >> 6, j = e & 63;
            t[i][j] = in[(size_t)(r0 + i) * DIM + c0 + j];
        }
        __syncthreads();
        for (int p = 0; p < 16; ++p) {
            int e = tid + p * 256, i = e >> 6, j = e & 63;
            out[(size_t)(c0 + i) * DIM + r0 + j] = f2bf(t[j][i]);
        }
    } else {
        const int n4x = NTOK * DIM / 4;
        const int n4p = NPOS * DIM / 4;
        const int fb = blockIdx.y * 12 + blockIdx.x;      // 0..143
        for (int idx = fb * 256 + tid; idx < n4x + n4p; idx += 144 * 256) {
            const float* src; ushort* dst; int j;
            if (idx < n4x) { src = x; dst = xb; j = idx; }
            else { src = rpe + (size_t)POS_OFF * DIM; dst = rpeb; j = idx - n4x; }
            float4 f = ((const float4*)src)[j];
            ushort o[4] = {f2bf(f.x), f2bf(f.y), f2bf(f.z), f2bf(f.w)};
            *(uint2*)&dst[(size_t)j * 4] = *(uint2*)o;
        }
    }
}

// ---------- combined projections: QKV (blocks 0..431) + pos (432..503) ----
__global__ __launch_bounds__(256) void proj_all(
    const ushort* __restrict__ xb, const ushort* __restrict__ rpeb,
    const ushort* __restrict__ wsT,
    const float* __restrict__ bq, const float* __restrict__ qbias,
    const float* __restrict__ bk, const float* __restrict__ bv,
    const float* __restrict__ vbias,
    ushort* __restrict__ qk, ushort* __restrict__ vT, ushort* __restrict__ posKQ)
{
    __shared__ ushort As[128 * 64];
    __shared__ ushort Bs[128 * 64];
    const int tid = threadIdx.x;
    const int lane = tid & 63, w = tid >> 6;
    const int id = blockIdx.x;
    const bool qkvP = id < 432;
    const ushort* A; const ushort* Bt; int m0, n0, M;
    if (qkvP) {
        m0 = (id % 24) * 128; n0 = (id / 24) * 128;
        A = xb; Bt = wsT; M = NTOK;
    } else {
        int p = id - 432;
        m0 = (p % 6) * 128; n0 = (p / 6) * 128;
        A = rpeb; Bt = wsT + (size_t)3 * DIM * DIM; M = NPOS;
    }
    const int lr = lane >> 3;
    const int lc = (lane & 7) ^ (lr & 7);
    const ushort* ga[4]; const ushort* gb[4];
#pragma unroll
    for (int p = 0; p < 4; ++p) {
        int row = (w * 4 + p) * 8 + lr;
        int arow = m0 + row; if (arow > M - 1) arow = M - 1;
        ga[p] = A + (size_t)arow * DIM + lc * 8;
        gb[p] = Bt + (size_t)(n0 + row) * DIM + lc * 8;
    }
    floatx4 acc[4][4] = {};
    const int qr = (w >> 1) * 64, qc = (w & 1) * 64;
    const int lm = lane & 15, lk = lane >> 4;
    for (int k0 = 0; k0 < DIM; k0 += 64) {
#pragma unroll
        for (int p = 0; p < 4; ++p) {
            gld16(ga[p], As + (w * 4 + p) * 512);
            gld16(gb[p], Bs + (w * 4 + p) * 512);
            ga[p] += 64; gb[p] += 64;
        }
        __syncthreads();
#pragma unroll
        for (int kk = 0; kk < 2; ++kk) {
            int ch = (kk * 4 + lk) ^ (lm & 7);
            short8 af[4], bf[4];
#pragma unroll
            for (int t = 0; t < 4; ++t) {
                af[t] = *(const short8*)&As[(qr + t * 16 + lm) * 64 + ch * 8];
                bf[t] = *(const short8*)&Bs[(qc + t * 16 + lm) * 64 + ch * 8];
            }
#pragma unroll
            for (int i = 0; i < 4; ++i)
#pragma unroll
                for (int j = 0; j < 4; ++j)
                    acc[i][j] = MFMA(af[i], bf[j], acc[i][j], 0, 0, 0);
        }
        __syncthreads();
    }
    if (qkvP) {
#pragma unroll
        for (int i = 0; i < 4; ++i) {
            int mbase = m0 + qr + i * 16 + (lane >> 4) * 4;
            int bb = mbase / SEQ;
            int s0 = mbase - bb * SEQ;
#pragma unroll
            for (int j = 0; j < 4; ++j) {
                int n = n0 + qc + j * 16 + lm;
                float bs;
                if (n < 768) bs = bq[n] + qbias[n];
                else if (n < QKN) bs = bk[n - 768];
                else bs = bv[n - QKN] + vbias[n - QKN];
                if (n < QKN) {
#pragma unroll
                    for (int r = 0; r < 4; ++r)
                        qk[(size_t)(mbase + r) * QKN + n] = f2bf(acc[i][j][r] + bs);
                } else {
                    int c = n - QKN, h = c >> 6, d = c & 63;
                    ushort tmp[4];
#pragma unroll
                    for (int r = 0; r < 4; ++r) tmp[r] = f2bf(acc[i][j][r] + bs);
                    *(uint2*)&vT[(((size_t)bb * NH + h) * DH + d) * SEQ + s0] = *(uint2*)tmp;
                }
            }
        }
    } else {
#pragma unroll
        for (int i = 0; i < 4; ++i) {
            int mbase = m0 + qr + i * 16 + (lane >> 4) * 4;
#pragma unroll
            for (int j = 0; j < 4; ++j) {
                int n = n0 + qc + j * 16 + lm;
#pragma unroll
                for (int r = 0; r < 4; ++r) {
                    int row = mbase + r;
                    if (row < NPOS)
                        posKQ[(size_t)row * PN + n] = f2bf(acc[i][j][r]);
                }
            }
        }
    }
}

// ---------- 128x64-tile MFMA GEMM (output projection, 288 blocks) ---------
__global__ __launch_bounds__(256) void gemm128x64(
    const ushort* __restrict__ A, const ushort* __restrict__ Bt,
    const float* __restrict__ bias, float* __restrict__ outF,
    int M, int N, int K)
{
    __shared__ ushort As[128 * 64];
    __shared__ ushort Bs[64 * 64];
    const int tid = threadIdx.x;
    const int lane = tid & 63, w = tid >> 6;
    const int n0 = blockIdx.x * 64, m0 = blockIdx.y * 128;
    const int lr = lane >> 3;
    const int lc = (lane & 7) ^ (lr & 7);
    const ushort* ga[4]; const ushort* gb[2];
#pragma unroll
    for (int p = 0; p < 4; ++p) {
        int arow = m0 + (w * 4 + p) * 8 + lr; if (arow > M - 1) arow = M - 1;
        ga[p] = A + (size_t)arow * K + lc * 8;
    }
#pragma unroll
    for (int p = 0; p < 2; ++p)
        gb[p] = Bt + (size_t)(n0 + (w * 2 + p) * 8 + lr) * K + lc * 8;
    floatx4 acc[4][2] = {};
    const int qr = (w >> 1) * 64, qc = (w & 1) * 32;
    const int lm = lane & 15, lk = lane >> 4;
    for (int k0 = 0; k0 < K; k0 += 64) {
#pragma unroll
        for (int p = 0; p < 4; ++p) { gld16(ga[p], As + (w * 4 + p) * 512); ga[p] += 64; }
#pragma unroll
        for (int p = 0; p < 2; ++p) { gld16(gb[p], Bs + (w * 2 + p) * 512); gb[p] += 64; }
        __syncthreads();
#pragma unroll
        for (int kk = 0; kk < 2; ++kk) {
            int ch = (kk * 4 + lk) ^ (lm & 7);
            short8 af[4], bf[2];
#pragma unroll
            for (int t = 0; t < 4; ++t)
                af[t] = *(const short8*)&As[(qr + t * 16 + lm) * 64 + ch * 8];
#pragma unroll
            for (int t = 0; t < 2; ++t)
                bf[t] = *(const short8*)&Bs[(qc + t * 16 + lm) * 64 + ch * 8];
#pragma unroll
            for (int i = 0; i < 4; ++i)
#pragma unroll
                for (int j = 0; j < 2; ++j)
                    acc[i][j] = MFMA(af[i], bf[j], acc[i][j], 0, 0, 0);
        }
        __syncthreads();
    }
#pragma unroll
    for (int i = 0; i < 4; ++i) {
        int mbase = m0 + qr + i * 16 + (lane >> 4) * 4;
#pragma unroll
        for (int j = 0; j < 2; ++j) {
            int n = n0 + qc + j * 16 + lm;
            float bs = bias[n];
#pragma unroll
            for (int r = 0; r < 4; ++r) {
                int row = mbase + r;
                if (row < M) outF[(size_t)row * N + n] = acc[i][j][r] + bs;
            }
        }
    }
}

// ---------- fused attention v12: coalesced acc regs + no persistent ptrs --
// grid (6, 12, 8), 512 threads (8 waves). LDS 44.25KB -> 3 blocks/CU
// (capacity 768 >= 576: single-round makespan). (512,6) caps total regs
// ~80/wave (unified VGPR+AGPR file). v11 spilled because the 5 phase-B
// sub-steps had INDEPENDENT accumulator pairs (~32-40 AGPRs reserved ->
// accum_offset 40 -> only 40 arch regs). v12: ONE reused A0/A1 acc pair
// + one reused fragment pair across all 5 sequential sub-steps (disjoint
// live ranges, sched_barrier(0) fences), and all global pointers rebuilt
// per-phase from kernel args + jt (no persistent pointer pairs).
// t=767 overread (i0=0, jt=5) lands in wsT pad; outputs band-masked.
__global__ __launch_bounds__(512, 6) void attn_fused12(
    const ushort* __restrict__ qk, const ushort* __restrict__ vT,
    const ushort* __restrict__ posKQ, ushort* __restrict__ aob)
{
    __shared__ ushort kt[64 * 64];        // 8 KB  k tile (swizzled)
    __shared__ ushort ccpt[2][64 * 72];   // 18 KB c2c scores / P (in-place), dbuf
    __shared__ ushort dqs[64 * 72];       // 9 KB  dq pre-shifted: [i][j]=dq[i][j-i+63]
    __shared__ ushort dks[64 * 72];       // 9 KB  dk pre-shifted: [i][j]=dk[j-i+63][j]
    __shared__ float rowsum[64];

    const int tid = threadIdx.x;
    const int lane = tid & 63, w = tid >> 6;
    const int i0 = blockIdx.x * 64;
    const int h = blockIdx.y, b = blockIdx.z;
    const int lm = lane & 15, lq = lane >> 4;

    if (tid < 64) rowsum[tid] = 0.f;

    // q fragments: register-resident (i-tile w>>1; two waves share a tile)
    short8 qf[2];
    {
        const ushort* qr = qk + (size_t)(b * SEQ + i0 + (w >> 1) * 16 + lm) * QKN + h * DH;
        qf[0] = *(const short8*)(qr + lq * 8);
        qf[1] = *(const short8*)(qr + 32 + lq * 8);
    }
    floatx4 occ[2] = {};

    const int t0i = 320 - i0;
    const int tcb = (w & 1) * 4;

    // stage j-tile 0 (k only); address built locally
    {
        int lr = lane >> 3, lc = (lane & 7) ^ ((lane >> 3) & 7);
        gld16(qk + (size_t)(b * SEQ + 8 * w + lr) * QKN + 768 + h * DH + lc * 8,
              kt + w * 512);
    }

    for (int jt = 0; jt < 6; ++jt) {
        const int j0 = jt * 64;
        ushort* cc = ccpt[jt & 1];

        __syncthreads();        // (1) kt staged; prev C (dqs/dks) + PV (other cc) done

        // ---- phase B: c2c + dq + dk -> bf16 buffers, unique writers ----
        const int tr = w >> 1;
        { // c2c: i-tile w>>1 x j-tiles (w&1)*2+{0,1}
            int tjb = (w & 1) * 2;
            floatx4 A0 = {}, A1 = {};
#pragma unroll
            for (int kk = 0; kk < 2; ++kk) {
                int ch = (kk * 4 + lq) ^ (lm & 7);
                short8 F0 = *(const short8*)&kt[(tjb * 16 + lm) * 64 + ch * 8];
                short8 F1 = *(const short8*)&kt[((tjb + 1) * 16 + lm) * 64 + ch * 8];
                A0 = MFMA(qf[kk], F0, A0, 0, 0, 0);
                A1 = MFMA(qf[kk], F1, A1, 0, 0, 0);
            }
#pragma unroll
            for (int r = 0; r < 4; ++r) {
                cc[(tr * 16 + lq * 4 + r) * 72 + tjb * 16 + lm] = f2bf(A0[r]);
                cc[(tr * 16 + lq * 4 + r) * 72 + (tjb + 1) * 16 + lm] = f2bf(A1[r]);
            }
        }
        __builtin_amdgcn_sched_barrier(0);
        { // dq: i-tile w>>1 x t-tiles (tcb+{0..3}); 2-tile halves, JIT L2 loads
            const ushort* dqb = posKQ + (size_t)(t0i + j0 + tcb * 16 + lm) * PN
                                + h * DH + lq * 8;
#pragma unroll
            for (int hf = 0; hf < 2; ++hf) {
                floatx4 A0 = {}, A1 = {};
#pragma unroll
                for (int kk = 0; kk < 2; ++kk) {
                    short8 F0 = *(const short8*)(dqb + (size_t)(hf * 2 + 0) * 16 * PN + kk * 32);
                    short8 F1 = *(const short8*)(dqb + (size_t)(hf * 2 + 1) * 16 * PN + kk * 32);
                    A0 = MFMA(qf[kk], F0, A0, 0, 0, 0);
                    A1 = MFMA(qf[kk], F1, A1, 0, 0, 0);
                }
#pragma unroll
                for (int s = 0; s < 2; ++s) {
                    int t = (tcb + hf * 2 + s) * 16 + lm;
#pragma unroll
                    for (int r = 0; r < 4; ++r) {
                        int i = tr * 16 + lq * 4 + r;
                        int j = t + i - 63;
                        float dv = s ? A1[r] : A0[r];
                        if ((unsigned)j < 64u) dqs[i * 72 + j] = f2bf(dv);
                    }
                }
                __builtin_amdgcn_sched_barrier(0);
            }
        }
        { // dk: t-tile w x j-tiles {0..3}; 2-tile halves, Qp JIT from L2
            const ushort* qpb = posKQ + (size_t)(t0i + j0 + w * 16 + lm) * PN
                                + 768 + h * DH + lq * 8;
#pragma unroll
            for (int hf = 0; hf < 2; ++hf) {
                floatx4 A0 = {}, A1 = {};
#pragma unroll
                for (int kk = 0; kk < 2; ++kk) {
                    short8 Fq = *(const short8*)(qpb + kk * 32);
                    int ch = (kk * 4 + lq) ^ (lm & 7);
                    short8 Fb = *(const short8*)&kt[((hf * 2 + 0) * 16 + lm) * 64 + ch * 8];
                    A0 = MFMA(Fq, Fb, A0, 0, 0, 0);
                    Fb = *(const short8*)&kt[((hf * 2 + 1) * 16 + lm) * 64 + ch * 8];
                    A1 = MFMA(Fq, Fb, A1, 0, 0, 0);
                }
#pragma unroll
                for (int s = 0; s < 2; ++s) {
                    int j = (hf * 2 + s) * 16 + lm;
#pragma unroll
                    for (int r = 0; r < 4; ++r) {
                        int t = w * 16 + lq * 4 + r;
                        int i = j - t + 63;
                        float ev = s ? A1[r] : A0[r];
                        if ((unsigned)i < 64u) dks[i * 72 + j] = f2bf(ev);
                    }
                }
                __builtin_amdgcn_sched_barrier(0);
            }
        }
        __syncthreads();        // (2) B done; kt free

        // issue next iter's k staging (overlaps phases C and D)
        if (jt < 5) {
            int lr = lane >> 3, lc = (lane & 7) ^ ((lane >> 3) & 7);
            gld16(qk + (size_t)(b * SEQ + j0 + 64 + 8 * w + lr) * QKN + 768 + h * DH + lc * 8,
                  kt + w * 512);
        }

        // ---- phase C: gather 3 terms (b128), exp, rowsum, P in place ----
        {
            int exr = tid >> 3, exseg = tid & 7;
            int off = exr * 72 + exseg * 8;
            uint4 c4 = *(const uint4*)&cc[off];
            uint4 q4 = *(const uint4*)&dqs[off];
            uint4 k4 = *(const uint4*)&dks[off];
            const ushort* cu = (const ushort*)&c4;
            const ushort* qu = (const ushort*)&q4;
            const ushort* ku = (const ushort*)&k4;
            float psum = 0.f;
            ushort pv[8];
#pragma unroll
            for (int c = 0; c < 8; ++c) {
                float sv = (bf2f(cu[c]) + bf2f(qu[c]) + bf2f(ku[c])) * 0.125f;
                float pe = __expf(sv);
                psum += pe;
                pv[c] = f2bf(pe);
            }
            psum += __shfl_xor(psum, 1);
            psum += __shfl_xor(psum, 2);
            psum += __shfl_xor(psum, 4);
            if (exseg == 0) rowsum[exr] += psum;
            *(uint4*)&cc[off] = *(uint4*)pv;
        }
        __syncthreads();        // (3) P visible

        // ---- phase D: PV accumulate; v direct-to-register -------------
        {
            int dtb = (w & 1) * 2;
#pragma unroll
            for (int t2 = 0; t2 < 2; ++t2) {
                int dt = dtb + t2;
                const ushort* vr = vT + ((size_t)(b * NH + h) * DH + dt * 16 + lm) * SEQ + j0;
                short8 vf0 = *(const short8*)(vr + lq * 8);
                short8 vf1 = *(const short8*)(vr + 32 + lq * 8);
                short8 af0 = *(const short8*)&cc[(tr * 16 + lm) * 72 + lq * 8];
                short8 af1 = *(const short8*)&cc[(tr * 16 + lm) * 72 + 32 + lq * 8];
                occ[t2] = MFMA(af0, vf0, occ[t2], 0, 0, 0);
                occ[t2] = MFMA(af1, vf1, occ[t2], 0, 0, 0);
            }
        }
        // no barrier: next iter's (1) protects cc (other buffer) and dqs/dks
    }

    {
        int tr = w >> 1, dtb = (w & 1) * 2;
#pragma unroll
        for (int t2 = 0; t2 < 2; ++t2) {
#pragma unroll
            for (int r = 0; r < 4; ++r) {
                int row = tr * 16 + lq * 4 + r;
                float ov = occ[t2][r] / rowsum[row];
                aob[(size_t)(b * SEQ + i0 + row) * DIM + h * DH + (dtb + t2) * 16 + lm] = f2bf(ov);
            }
        }
    }
}

extern "C" void kernel_launch(void* const* d_in, const int* in_sizes, int n_in,
                              void* d_out, int out_size, void* d_ws, size_t ws_size,
                              hipStream_t stream) {
    const float* x   = (const float*)d_in[0];
    const float* rpe = (const float*)d_in[1];
    const float* Wq  = (const float*)d_in[2];
    const float* bq  = (const float*)d_in[3];
    const float* Wk  = (const float*)d_in[4];
    const float* bk  = (const float*)d_in[5];
    const float* Wv  = (const float*)d_in[6];
    const float* bv  = (const float*)d_in[7];
    const float* qbias = (const float*)d_in[8];
    const float* vbias = (const float*)d_in[9];
    const float* Wpk = (const float*)d_in[10];
    const float* Wpq = (const float*)d_in[11];
    const float* Wo  = (const float*)d_in[12];
    const float* bo  = (const float*)d_in[13];
    float* out = (float*)d_out;

    char* ws = (char*)d_ws;
    ushort* xb    = (ushort*)ws; ws += (size_t)NTOK * DIM * 2;
    ushort* qkbuf = (ushort*)ws; ws += (size_t)NTOK * QKN * 2;
    ushort* vT    = (ushort*)ws; ws += (size_t)NTOK * DIM * 2;
    ushort* aob   = (ushort*)ws; ws += (size_t)NTOK * DIM * 2;
    ushort* rpeb  = (ushort*)ws; ws += (size_t)NPOS * DIM * 2;
    ushort* posKQ = (ushort*)ws; ws += (size_t)NPOS * PN * 2;
    ushort* wsT   = (ushort*)ws; ws += (size_t)6 * DIM * DIM * 2;   // must follow posKQ (t=767 overread pad)

    // 1) converts + weight transposes
    prep<<<dim3(12, 12, 7), dim3(256), 0, stream>>>(
        Wq, Wk, Wv, Wpk, Wpq, Wo, x, rpe, wsT, xb, rpeb);
    // 2) QKV projection + positional projections in one launch (504 blocks)
    proj_all<<<dim3(504), dim3(256), 0, stream>>>(
        xb, rpeb, wsT, bq, qbias, bk, bv, vbias, qkbuf, vT, posKQ);
    // 3) fused attention v12 (44.25KB LDS, 3 blocks/CU, coalesced acc regs)
    attn_fused12<<<dim3(SEQ / 64, NH, BATCH), dim3(512), 0, stream>>>(qkbuf, vT, posKQ, aob);
    // 4) output projection -> fp32 d_out (288 blocks)
    gemm128x64<<<dim3(DIM / 64, NTOK / 128), dim3(256), 0, stream>>>(
        aob, wsT + (size_t)5 * DIM * DIM, bo, out, NTOK, DIM, DIM);
}

// Round 5
// 213.777 us; speedup vs baseline: 1.4240x; 1.0385x over previous
//
#include <hip/hip_runtime.h>
#include <hip/hip_bf16.h>
#include <math.h>

#define BATCH 8
#define SEQ 384
#define DIM 768
#define NH 12
#define DH 64
#define NPOS 767
#define POS_OFF 128
#define NTOK (BATCH * SEQ)
#define QKN 1536
#define QKVN 2304
#define PN 1536

typedef __attribute__((ext_vector_type(8))) short short8;
typedef __attribute__((ext_vector_type(4))) float floatx4;
typedef unsigned int u32;

__device__ __forceinline__ ushort f2bf(float f) {
    __hip_bfloat16 h = __float2bfloat16(f);
    return *reinterpret_cast<ushort*>(&h);
}
__device__ __forceinline__ float bf2f(ushort u) {
    u32 x = ((u32)u) << 16;
    float f; __builtin_memcpy(&f, &x, 4); return f;
}

// async global->LDS, 16B per lane; lds dest = wave-uniform base + lane*16
__device__ __forceinline__ void gld16(const ushort* g, ushort* l) {
    __builtin_amdgcn_global_load_lds(
        (const __attribute__((address_space(1))) u32*)g,
        (__attribute__((address_space(3))) u32*)l, 16, 0, 0);
}

#define MFMA __builtin_amdgcn_mfma_f32_16x16x32_bf16

// ---------- prep: weight transposes (z<6) + row converts (z==6) -----------
__global__ __launch_bounds__(256) void prep(
    const float* W0, const float* W1, const float* W2,
    const float* W3, const float* W4, const float* W5,
    const float* x, const float* rpe,
    ushort* __restrict__ wsT, ushort* __restrict__ xb, ushort* __restrict__ rpeb)
{
    const int tid = threadIdx.x;
    if (blockIdx.z < 6) {
        __shared__ float t[64][65];
        const float* srcs[6] = {W0, W1, W2, W3, W4, W5};
        const float* in = srcs[blockIdx.z];
        ushort* out = wsT + (size_t)blockIdx.z * DIM * DIM;
        const int r0 = blockIdx.y * 64, c0 = blockIdx.x * 64;
        for (int p = 0; p < 16; ++p) {
            int e = tid + p * 256, i = e >> 6, j = e & 63;
            t[i][j] = in[(size_t)(r0 + i) * DIM + c0 + j];
        }
        __syncthreads();
        for (int p = 0; p < 16; ++p) {
            int e = tid + p * 256, i = e >> 6, j = e & 63;
            out[(size_t)(c0 + i) * DIM + r0 + j] = f2bf(t[j][i]);
        }
    } else {
        const int n4x = NTOK * DIM / 4;
        const int n4p = NPOS * DIM / 4;
        const int fb = blockIdx.y * 12 + blockIdx.x;      // 0..143
        for (int idx = fb * 256 + tid; idx < n4x + n4p; idx += 144 * 256) {
            const float* src; ushort* dst; int j;
            if (idx < n4x) { src = x; dst = xb; j = idx; }
            else { src = rpe + (size_t)POS_OFF * DIM; dst = rpeb; j = idx - n4x; }
            float4 f = ((const float4*)src)[j];
            ushort o[4] = {f2bf(f.x), f2bf(f.y), f2bf(f.z), f2bf(f.w)};
            *(uint2*)&dst[(size_t)j * 4] = *(uint2*)o;
        }
    }
}

// ---------- combined projections: QKV (blocks 0..431) + pos (432..503) ----
__global__ __launch_bounds__(256) void proj_all(
    const ushort* __restrict__ xb, const ushort* __restrict__ rpeb,
    const ushort* __restrict__ wsT,
    const float* __restrict__ bq, const float* __restrict__ qbias,
    const float* __restrict__ bk, const float* __restrict__ bv,
    const float* __restrict__ vbias,
    ushort* __restrict__ qk, ushort* __restrict__ vT, ushort* __restrict__ posKQ)
{
    __shared__ ushort As[128 * 64];
    __shared__ ushort Bs[128 * 64];
    const int tid = threadIdx.x;
    const int lane = tid & 63, w = tid >> 6;
    const int id = blockIdx.x;
    const bool qkvP = id < 432;
    const ushort* A; const ushort* Bt; int m0, n0, M;
    if (qkvP) {
        m0 = (id % 24) * 128; n0 = (id / 24) * 128;
        A = xb; Bt = wsT; M = NTOK;
    } else {
        int p = id - 432;
        m0 = (p % 6) * 128; n0 = (p / 6) * 128;
        A = rpeb; Bt = wsT + (size_t)3 * DIM * DIM; M = NPOS;
    }
    const int lr = lane >> 3;
    const int lc = (lane & 7) ^ (lr & 7);
    const ushort* ga[4]; const ushort* gb[4];
#pragma unroll
    for (int p = 0; p < 4; ++p) {
        int row = (w * 4 + p) * 8 + lr;
        int arow = m0 + row; if (arow > M - 1) arow = M - 1;
        ga[p] = A + (size_t)arow * DIM + lc * 8;
        gb[p] = Bt + (size_t)(n0 + row) * DIM + lc * 8;
    }
    floatx4 acc[4][4] = {};
    const int qr = (w >> 1) * 64, qc = (w & 1) * 64;
    const int lm = lane & 15, lk = lane >> 4;
    for (int k0 = 0; k0 < DIM; k0 += 64) {
#pragma unroll
        for (int p = 0; p < 4; ++p) {
            gld16(ga[p], As + (w * 4 + p) * 512);
            gld16(gb[p], Bs + (w * 4 + p) * 512);
            ga[p] += 64; gb[p] += 64;
        }
        __syncthreads();
#pragma unroll
        for (int kk = 0; kk < 2; ++kk) {
            int ch = (kk * 4 + lk) ^ (lm & 7);
            short8 af[4], bf[4];
#pragma unroll
            for (int t = 0; t < 4; ++t) {
                af[t] = *(const short8*)&As[(qr + t * 16 + lm) * 64 + ch * 8];
                bf[t] = *(const short8*)&Bs[(qc + t * 16 + lm) * 64 + ch * 8];
            }
#pragma unroll
            for (int i = 0; i < 4; ++i)
#pragma unroll
                for (int j = 0; j < 4; ++j)
                    acc[i][j] = MFMA(af[i], bf[j], acc[i][j], 0, 0, 0);
        }
        __syncthreads();
    }
    if (qkvP) {
#pragma unroll
        for (int i = 0; i < 4; ++i) {
            int mbase = m0 + qr + i * 16 + (lane >> 4) * 4;
            int bb = mbase / SEQ;
            int s0 = mbase - bb * SEQ;
#pragma unroll
            for (int j = 0; j < 4; ++j) {
                int n = n0 + qc + j * 16 + lm;
                float bs;
                if (n < 768) bs = bq[n] + qbias[n];
                else if (n < QKN) bs = bk[n - 768];
                else bs = bv[n - QKN] + vbias[n - QKN];
                if (n < QKN) {
#pragma unroll
                    for (int r = 0; r < 4; ++r)
                        qk[(size_t)(mbase + r) * QKN + n] = f2bf(acc[i][j][r] + bs);
                } else {
                    int c = n - QKN, h = c >> 6, d = c & 63;
                    ushort tmp[4];
#pragma unroll
                    for (int r = 0; r < 4; ++r) tmp[r] = f2bf(acc[i][j][r] + bs);
                    *(uint2*)&vT[(((size_t)bb * NH + h) * DH + d) * SEQ + s0] = *(uint2*)tmp;
                }
            }
        }
    } else {
#pragma unroll
        for (int i = 0; i < 4; ++i) {
            int mbase = m0 + qr + i * 16 + (lane >> 4) * 4;
#pragma unroll
            for (int j = 0; j < 4; ++j) {
                int n = n0 + qc + j * 16 + lm;
#pragma unroll
                for (int r = 0; r < 4; ++r) {
                    int row = mbase + r;
                    if (row < NPOS)
                        posKQ[(size_t)row * PN + n] = f2bf(acc[i][j][r]);
                }
            }
        }
    }
}

// ---------- 128x64-tile MFMA GEMM (output projection, 288 blocks) ---------
__global__ __launch_bounds__(256) void gemm128x64(
    const ushort* __restrict__ A, const ushort* __restrict__ Bt,
    const float* __restrict__ bias, float* __restrict__ outF,
    int M, int N, int K)
{
    __shared__ ushort As[128 * 64];
    __shared__ ushort Bs[64 * 64];
    const int tid = threadIdx.x;
    const int lane = tid & 63, w = tid >> 6;
    const int n0 = blockIdx.x * 64, m0 = blockIdx.y * 128;
    const int lr = lane >> 3;
    const int lc = (lane & 7) ^ (lr & 7);
    const ushort* ga[4]; const ushort* gb[2];
#pragma unroll
    for (int p = 0; p < 4; ++p) {
        int arow = m0 + (w * 4 + p) * 8 + lr; if (arow > M - 1) arow = M - 1;
        ga[p] = A + (size_t)arow * K + lc * 8;
    }
#pragma unroll
    for (int p = 0; p < 2; ++p)
        gb[p] = Bt + (size_t)(n0 + (w * 2 + p) * 8 + lr) * K + lc * 8;
    floatx4 acc[4][2] = {};
    const int qr = (w >> 1) * 64, qc = (w & 1) * 32;
    const int lm = lane & 15, lk = lane >> 4;
    for (int k0 = 0; k0 < K; k0 += 64) {
#pragma unroll
        for (int p = 0; p < 4; ++p) { gld16(ga[p], As + (w * 4 + p) * 512); ga[p] += 64; }
#pragma unroll
        for (int p = 0; p < 2; ++p) { gld16(gb[p], Bs + (w * 2 + p) * 512); gb[p] += 64; }
        __syncthreads();
#pragma unroll
        for (int kk = 0; kk < 2; ++kk) {
            int ch = (kk * 4 + lk) ^ (lm & 7);
            short8 af[4], bf[2];
#pragma unroll
            for (int t = 0; t < 4; ++t)
                af[t] = *(const short8*)&As[(qr + t * 16 + lm) * 64 + ch * 8];
#pragma unroll
            for (int t = 0; t < 2; ++t)
                bf[t] = *(const short8*)&Bs[(qc + t * 16 + lm) * 64 + ch * 8];
#pragma unroll
            for (int i = 0; i < 4; ++i)
#pragma unroll
                for (int j = 0; j < 2; ++j)
                    acc[i][j] = MFMA(af[i], bf[j], acc[i][j], 0, 0, 0);
        }
        __syncthreads();
    }
#pragma unroll
    for (int i = 0; i < 4; ++i) {
        int mbase = m0 + qr + i * 16 + (lane >> 4) * 4;
#pragma unroll
        for (int j = 0; j < 2; ++j) {
            int n = n0 + qc + j * 16 + lm;
            float bs = bias[n];
#pragma unroll
            for (int r = 0; r < 4; ++r) {
                int row = mbase + r;
                if (row < M) outF[(size_t)row * N + n] = acc[i][j][r] + bs;
            }
        }
    }
}

// ---------- fused attention v13: v12 body, UNCAPPED registers -------------
// grid (6, 12, 8), 512 threads (8 waves). LDS 44.25KB.
// v9-v12 lesson: forcing (512,6) (~80-reg budget) makes the allocator
// split 40 arch + 40 acc and spill ~27 regs/thread (~31MB/way scratch
// traffic ~ 60us of HBM time). This body naturally wants ~100 regs.
// v13 drops the cap: if natural alloc <= 85 -> 3 blocks/CU (LDS-limited,
// single-round makespan) with ZERO spill; if 86-128 -> 2 blocks/CU, still
// zero spill, v8-parity-or-better (v13 has no kps/qps DMA staging).
// Either outcome beats the capped+spilling 83us.
// t=767 overread (i0=0, jt=5) lands in wsT pad; outputs band-masked.
__global__ __launch_bounds__(512, 2) void attn_fused13(
    const ushort* __restrict__ qk, const ushort* __restrict__ vT,
    const ushort* __restrict__ posKQ, ushort* __restrict__ aob)
{
    __shared__ ushort kt[64 * 64];        // 8 KB  k tile (swizzled)
    __shared__ ushort ccpt[2][64 * 72];   // 18 KB c2c scores / P (in-place), dbuf
    __shared__ ushort dqs[64 * 72];       // 9 KB  dq pre-shifted: [i][j]=dq[i][j-i+63]
    __shared__ ushort dks[64 * 72];       // 9 KB  dk pre-shifted: [i][j]=dk[j-i+63][j]
    __shared__ float rowsum[64];

    const int tid = threadIdx.x;
    const int lane = tid & 63, w = tid >> 6;
    const int i0 = blockIdx.x * 64;
    const int h = blockIdx.y, b = blockIdx.z;
    const int lm = lane & 15, lq = lane >> 4;

    if (tid < 64) rowsum[tid] = 0.f;

    // q fragments: register-resident (i-tile w>>1; two waves share a tile)
    short8 qf[2];
    {
        const ushort* qr = qk + (size_t)(b * SEQ + i0 + (w >> 1) * 16 + lm) * QKN + h * DH;
        qf[0] = *(const short8*)(qr + lq * 8);
        qf[1] = *(const short8*)(qr + 32 + lq * 8);
    }
    floatx4 occ[2] = {};

    const int t0i = 320 - i0;
    const int tcb = (w & 1) * 4;

    // stage j-tile 0 (k only); address built locally
    {
        int lr = lane >> 3, lc = (lane & 7) ^ ((lane >> 3) & 7);
        gld16(qk + (size_t)(b * SEQ + 8 * w + lr) * QKN + 768 + h * DH + lc * 8,
              kt + w * 512);
    }

    for (int jt = 0; jt < 6; ++jt) {
        const int j0 = jt * 64;
        ushort* cc = ccpt[jt & 1];

        __syncthreads();        // (1) kt staged; prev C (dqs/dks) + PV (other cc) done

        // ---- phase B: c2c + dq + dk -> bf16 buffers, unique writers ----
        const int tr = w >> 1;
        { // c2c: i-tile w>>1 x j-tiles (w&1)*2+{0,1}
            int tjb = (w & 1) * 2;
            floatx4 A0 = {}, A1 = {};
#pragma unroll
            for (int kk = 0; kk < 2; ++kk) {
                int ch = (kk * 4 + lq) ^ (lm & 7);
                short8 F0 = *(const short8*)&kt[(tjb * 16 + lm) * 64 + ch * 8];
                short8 F1 = *(const short8*)&kt[((tjb + 1) * 16 + lm) * 64 + ch * 8];
                A0 = MFMA(qf[kk], F0, A0, 0, 0, 0);
                A1 = MFMA(qf[kk], F1, A1, 0, 0, 0);
            }
#pragma unroll
            for (int r = 0; r < 4; ++r) {
                cc[(tr * 16 + lq * 4 + r) * 72 + tjb * 16 + lm] = f2bf(A0[r]);
                cc[(tr * 16 + lq * 4 + r) * 72 + (tjb + 1) * 16 + lm] = f2bf(A1[r]);
            }
        }
        __builtin_amdgcn_sched_barrier(0);
        { // dq: i-tile w>>1 x t-tiles (tcb+{0..3}); 2-tile halves, JIT L2 loads
            const ushort* dqb = posKQ + (size_t)(t0i + j0 + tcb * 16 + lm) * PN
                                + h * DH + lq * 8;
#pragma unroll
            for (int hf = 0; hf < 2; ++hf) {
                floatx4 A0 = {}, A1 = {};
#pragma unroll
                for (int kk = 0; kk < 2; ++kk) {
                    short8 F0 = *(const short8*)(dqb + (size_t)(hf * 2 + 0) * 16 * PN + kk * 32);
                    short8 F1 = *(const short8*)(dqb + (size_t)(hf * 2 + 1) * 16 * PN + kk * 32);
                    A0 = MFMA(qf[kk], F0, A0, 0, 0, 0);
                    A1 = MFMA(qf[kk], F1, A1, 0, 0, 0);
                }
#pragma unroll
                for (int s = 0; s < 2; ++s) {
                    int t = (tcb + hf * 2 + s) * 16 + lm;
#pragma unroll
                    for (int r = 0; r < 4; ++r) {
                        int i = tr * 16 + lq * 4 + r;
                        int j = t + i - 63;
                        float dv = s ? A1[r] : A0[r];
                        if ((unsigned)j < 64u) dqs[i * 72 + j] = f2bf(dv);
                    }
                }
                __builtin_amdgcn_sched_barrier(0);
            }
        }
        { // dk: t-tile w x j-tiles {0..3}; 2-tile halves, Qp JIT from L2
            const ushort* qpb = posKQ + (size_t)(t0i + j0 + w * 16 + lm) * PN
                                + 768 + h * DH + lq * 8;
#pragma unroll
            for (int hf = 0; hf < 2; ++hf) {
                floatx4 A0 = {}, A1 = {};
#pragma unroll
                for (int kk = 0; kk < 2; ++kk) {
                    short8 Fq = *(const short8*)(qpb + kk * 32);
                    int ch = (kk * 4 + lq) ^ (lm & 7);
                    short8 Fb = *(const short8*)&kt[((hf * 2 + 0) * 16 + lm) * 64 + ch * 8];
                    A0 = MFMA(Fq, Fb, A0, 0, 0, 0);
                    Fb = *(const short8*)&kt[((hf * 2 + 1) * 16 + lm) * 64 + ch * 8];
                    A1 = MFMA(Fq, Fb, A1, 0, 0, 0);
                }
#pragma unroll
                for (int s = 0; s < 2; ++s) {
                    int j = (hf * 2 + s) * 16 + lm;
#pragma unroll
                    for (int r = 0; r < 4; ++r) {
                        int t = w * 16 + lq * 4 + r;
                        int i = j - t + 63;
                        float ev = s ? A1[r] : A0[r];
                        if ((unsigned)i < 64u) dks[i * 72 + j] = f2bf(ev);
                    }
                }
                __builtin_amdgcn_sched_barrier(0);
            }
        }
        __syncthreads();        // (2) B done; kt free

        // issue next iter's k staging (overlaps phases C and D)
        if (jt < 5) {
            int lr = lane >> 3, lc = (lane & 7) ^ ((lane >> 3) & 7);
            gld16(qk + (size_t)(b * SEQ + j0 + 64 + 8 * w + lr) * QKN + 768 + h * DH + lc * 8,
                  kt + w * 512);
        }

        // ---- phase C: gather 3 terms (b128), exp, rowsum, P in place ----
        {
            int exr = tid >> 3, exseg = tid & 7;
            int off = exr * 72 + exseg * 8;
            uint4 c4 = *(const uint4*)&cc[off];
            uint4 q4 = *(const uint4*)&dqs[off];
            uint4 k4 = *(const uint4*)&dks[off];
            const ushort* cu = (const ushort*)&c4;
            const ushort* qu = (const ushort*)&q4;
            const ushort* ku = (const ushort*)&k4;
            float psum = 0.f;
            ushort pv[8];
#pragma unroll
            for (int c = 0; c < 8; ++c) {
                float sv = (bf2f(cu[c]) + bf2f(qu[c]) + bf2f(ku[c])) * 0.125f;
                float pe = __expf(sv);
                psum += pe;
                pv[c] = f2bf(pe);
            }
            psum += __shfl_xor(psum, 1);
            psum += __shfl_xor(psum, 2);
            psum += __shfl_xor(psum, 4);
            if (exseg == 0) rowsum[exr] += psum;
            *(uint4*)&cc[off] = *(uint4*)pv;
        }
        __syncthreads();        // (3) P visible

        // ---- phase D: PV accumulate; v direct-to-register -------------
        {
            int dtb = (w & 1) * 2;
#pragma unroll
            for (int t2 = 0; t2 < 2; ++t2) {
                int dt = dtb + t2;
                const ushort* vr = vT + ((size_t)(b * NH + h) * DH + dt * 16 + lm) * SEQ + j0;
                short8 vf0 = *(const short8*)(vr + lq * 8);
                short8 vf1 = *(const short8*)(vr + 32 + lq * 8);
                short8 af0 = *(const short8*)&cc[(tr * 16 + lm) * 72 + lq * 8];
                short8 af1 = *(const short8*)&cc[(tr * 16 + lm) * 72 + 32 + lq * 8];
                occ[t2] = MFMA(af0, vf0, occ[t2], 0, 0, 0);
                occ[t2] = MFMA(af1, vf1, occ[t2], 0, 0, 0);
            }
        }
        // no barrier: next iter's (1) protects cc (other buffer) and dqs/dks
    }

    {
        int tr = w >> 1, dtb = (w & 1) * 2;
#pragma unroll
        for (int t2 = 0; t2 < 2; ++t2) {
#pragma unroll
            for (int r = 0; r < 4; ++r) {
                int row = tr * 16 + lq * 4 + r;
                float ov = occ[t2][r] / rowsum[row];
                aob[(size_t)(b * SEQ + i0 + row) * DIM + h * DH + (dtb + t2) * 16 + lm] = f2bf(ov);
            }
        }
    }
}

extern "C" void kernel_launch(void* const* d_in, const int* in_sizes, int n_in,
                              void* d_out, int out_size, void* d_ws, size_t ws_size,
                              hipStream_t stream) {
    const float* x   = (const float*)d_in[0];
    const float* rpe = (const float*)d_in[1];
    const float* Wq  = (const float*)d_in[2];
    const float* bq  = (const float*)d_in[3];
    const float* Wk  = (const float*)d_in[4];
    const float* bk  = (const float*)d_in[5];
    const float* Wv  = (const float*)d_in[6];
    const float* bv  = (const float*)d_in[7];
    const float* qbias = (const float*)d_in[8];
    const float* vbias = (const float*)d_in[9];
    const float* Wpk = (const float*)d_in[10];
    const float* Wpq = (const float*)d_in[11];
    const float* Wo  = (const float*)d_in[12];
    const float* bo  = (const float*)d_in[13];
    float* out = (float*)d_out;

    char* ws = (char*)d_ws;
    ushort* xb    = (ushort*)ws; ws += (size_t)NTOK * DIM * 2;
    ushort* qkbuf = (ushort*)ws; ws += (size_t)NTOK * QKN * 2;
    ushort* vT    = (ushort*)ws; ws += (size_t)NTOK * DIM * 2;
    ushort* aob   = (ushort*)ws; ws += (size_t)NTOK * DIM * 2;
    ushort* rpeb  = (ushort*)ws; ws += (size_t)NPOS * DIM * 2;
    ushort* posKQ = (ushort*)ws; ws += (size_t)NPOS * PN * 2;
    ushort* wsT   = (ushort*)ws; ws += (size_t)6 * DIM * DIM * 2;   // must follow posKQ (t=767 overread pad)

    // 1) converts + weight transposes
    prep<<<dim3(12, 12, 7), dim3(256), 0, stream>>>(
        Wq, Wk, Wv, Wpk, Wpq, Wo, x, rpe, wsT, xb, rpeb);
    // 2) QKV projection + positional projections in one launch (504 blocks)
    proj_all<<<dim3(504), dim3(256), 0, stream>>>(
        xb, rpeb, wsT, bq, qbias, bk, bv, vbias, qkbuf, vT, posKQ);
    // 3) fused attention v13 (44.25KB LDS, natural regs, zero spill)
    attn_fused13<<<dim3(SEQ / 64, NH, BATCH), dim3(512), 0, stream>>>(qkbuf, vT, posKQ, aob);
    // 4) output projection -> fp32 d_out (288 blocks)
    gemm128x64<<<dim3(DIM / 64, NTOK / 128), dim3(256), 0, stream>>>(
        aob, wsT + (size_t)5 * DIM * DIM, bo, out, NTOK, DIM, DIM);
}

// Round 6
// 180.693 us; speedup vs baseline: 1.6847x; 1.1831x over previous
//
#include <hip/hip_runtime.h>
#include <hip/hip_bf16.h>
#include <math.h>

#define BATCH 8
#define SEQ 384
#define DIM 768
#define NH 12
#define DH 64
#define NPOS 767
#define POS_OFF 128
#define NTOK (BATCH * SEQ)
#define QKN 1536
#define QKVN 2304
#define PN 1536

typedef __attribute__((ext_vector_type(8))) short short8;
typedef __attribute__((ext_vector_type(4))) float floatx4;
typedef unsigned int u32;

__device__ __forceinline__ ushort f2bf(float f) {
    __hip_bfloat16 h = __float2bfloat16(f);
    return *reinterpret_cast<ushort*>(&h);
}
__device__ __forceinline__ float bf2f(ushort u) {
    u32 x = ((u32)u) << 16;
    float f; __builtin_memcpy(&f, &x, 4); return f;
}

// async global->LDS, 16B per lane; lds dest = wave-uniform base + lane*16
__device__ __forceinline__ void gld16(const ushort* g, ushort* l) {
    __builtin_amdgcn_global_load_lds(
        (const __attribute__((address_space(1))) u32*)g,
        (__attribute__((address_space(3))) u32*)l, 16, 0, 0);
}

#define MFMA __builtin_amdgcn_mfma_f32_16x16x32_bf16

// ---------- prep: weight transposes (z<6) + row converts (z==6) -----------
__global__ __launch_bounds__(256) void prep(
    const float* W0, const float* W1, const float* W2,
    const float* W3, const float* W4, const float* W5,
    const float* x, const float* rpe,
    ushort* __restrict__ wsT, ushort* __restrict__ xb, ushort* __restrict__ rpeb)
{
    const int tid = threadIdx.x;
    if (blockIdx.z < 6) {
        __shared__ float t[64][65];
        const float* srcs[6] = {W0, W1, W2, W3, W4, W5};
        const float* in = srcs[blockIdx.z];
        ushort* out = wsT + (size_t)blockIdx.z * DIM * DIM;
        const int r0 = blockIdx.y * 64, c0 = blockIdx.x * 64;
        for (int p = 0; p < 16; ++p) {
            int e = tid + p * 256, i = e >> 6, j = e & 63;
            t[i][j] = in[(size_t)(r0 + i) * DIM + c0 + j];
        }
        __syncthreads();
        for (int p = 0; p < 16; ++p) {
            int e = tid + p * 256, i = e >> 6, j = e & 63;
            out[(size_t)(c0 + i) * DIM + r0 + j] = f2bf(t[j][i]);
        }
    } else {
        const int n4x = NTOK * DIM / 4;
        const int n4p = NPOS * DIM / 4;
        const int fb = blockIdx.y * 12 + blockIdx.x;      // 0..143
        for (int idx = fb * 256 + tid; idx < n4x + n4p; idx += 144 * 256) {
            const float* src; ushort* dst; int j;
            if (idx < n4x) { src = x; dst = xb; j = idx; }
            else { src = rpe + (size_t)POS_OFF * DIM; dst = rpeb; j = idx - n4x; }
            float4 f = ((const float4*)src)[j];
            ushort o[4] = {f2bf(f.x), f2bf(f.y), f2bf(f.z), f2bf(f.w)};
            *(uint2*)&dst[(size_t)j * 4] = *(uint2*)o;
        }
    }
}

// ---------- combined projections: QKV (blocks 0..431) + pos (432..503) ----
__global__ __launch_bounds__(256) void proj_all(
    const ushort* __restrict__ xb, const ushort* __restrict__ rpeb,
    const ushort* __restrict__ wsT,
    const float* __restrict__ bq, const float* __restrict__ qbias,
    const float* __restrict__ bk, const float* __restrict__ bv,
    const float* __restrict__ vbias,
    ushort* __restrict__ qk, ushort* __restrict__ vT, ushort* __restrict__ posKQ)
{
    __shared__ ushort As[128 * 64];
    __shared__ ushort Bs[128 * 64];
    const int tid = threadIdx.x;
    const int lane = tid & 63, w = tid >> 6;
    const int id = blockIdx.x;
    const bool qkvP = id < 432;
    const ushort* A; const ushort* Bt; int m0, n0, M;
    if (qkvP) {
        m0 = (id % 24) * 128; n0 = (id / 24) * 128;
        A = xb; Bt = wsT; M = NTOK;
    } else {
        int p = id - 432;
        m0 = (p % 6) * 128; n0 = (p / 6) * 128;
        A = rpeb; Bt = wsT + (size_t)3 * DIM * DIM; M = NPOS;
    }
    const int lr = lane >> 3;
    const int lc = (lane & 7) ^ (lr & 7);
    const ushort* ga[4]; const ushort* gb[4];
#pragma unroll
    for (int p = 0; p < 4; ++p) {
        int row = (w * 4 + p) * 8 + lr;
        int arow = m0 + row; if (arow > M - 1) arow = M - 1;
        ga[p] = A + (size_t)arow * DIM + lc * 8;
        gb[p] = Bt + (size_t)(n0 + row) * DIM + lc * 8;
    }
    floatx4 acc[4][4] = {};
    const int qr = (w >> 1) * 64, qc = (w & 1) * 64;
    const int lm = lane & 15, lk = lane >> 4;
    for (int k0 = 0; k0 < DIM; k0 += 64) {
#pragma unroll
        for (int p = 0; p < 4; ++p) {
            gld16(ga[p], As + (w * 4 + p) * 512);
            gld16(gb[p], Bs + (w * 4 + p) * 512);
            ga[p] += 64; gb[p] += 64;
        }
        __syncthreads();
#pragma unroll
        for (int kk = 0; kk < 2; ++kk) {
            int ch = (kk * 4 + lk) ^ (lm & 7);
            short8 af[4], bf[4];
#pragma unroll
            for (int t = 0; t < 4; ++t) {
                af[t] = *(const short8*)&As[(qr + t * 16 + lm) * 64 + ch * 8];
                bf[t] = *(const short8*)&Bs[(qc + t * 16 + lm) * 64 + ch * 8];
            }
#pragma unroll
            for (int i = 0; i < 4; ++i)
#pragma unroll
                for (int j = 0; j < 4; ++j)
                    acc[i][j] = MFMA(af[i], bf[j], acc[i][j], 0, 0, 0);
        }
        __syncthreads();
    }
    if (qkvP) {
#pragma unroll
        for (int i = 0; i < 4; ++i) {
            int mbase = m0 + qr + i * 16 + (lane >> 4) * 4;
            int bb = mbase / SEQ;
            int s0 = mbase - bb * SEQ;
#pragma unroll
            for (int j = 0; j < 4; ++j) {
                int n = n0 + qc + j * 16 + lm;
                float bs;
                if (n < 768) bs = bq[n] + qbias[n];
                else if (n < QKN) bs = bk[n - 768];
                else bs = bv[n - QKN] + vbias[n - QKN];
                if (n < QKN) {
#pragma unroll
                    for (int r = 0; r < 4; ++r)
                        qk[(size_t)(mbase + r) * QKN + n] = f2bf(acc[i][j][r] + bs);
                } else {
                    int c = n - QKN, h = c >> 6, d = c & 63;
                    ushort tmp[4];
#pragma unroll
                    for (int r = 0; r < 4; ++r) tmp[r] = f2bf(acc[i][j][r] + bs);
                    *(uint2*)&vT[(((size_t)bb * NH + h) * DH + d) * SEQ + s0] = *(uint2*)tmp;
                }
            }
        }
    } else {
#pragma unroll
        for (int i = 0; i < 4; ++i) {
            int mbase = m0 + qr + i * 16 + (lane >> 4) * 4;
#pragma unroll
            for (int j = 0; j < 4; ++j) {
                int n = n0 + qc + j * 16 + lm;
#pragma unroll
                for (int r = 0; r < 4; ++r) {
                    int row = mbase + r;
                    if (row < NPOS)
                        posKQ[(size_t)row * PN + n] = f2bf(acc[i][j][r]);
                }
            }
        }
    }
}

// ---------- 128x64-tile MFMA GEMM (output projection, 288 blocks) ---------
__global__ __launch_bounds__(256) void gemm128x64(
    const ushort* __restrict__ A, const ushort* __restrict__ Bt,
    const float* __restrict__ bias, float* __restrict__ outF,
    int M, int N, int K)
{
    __shared__ ushort As[128 * 64];
    __shared__ ushort Bs[64 * 64];
    const int tid = threadIdx.x;
    const int lane = tid & 63, w = tid >> 6;
    const int n0 = blockIdx.x * 64, m0 = blockIdx.y * 128;
    const int lr = lane >> 3;
    const int lc = (lane & 7) ^ (lr & 7);
    const ushort* ga[4]; const ushort* gb[2];
#pragma unroll
    for (int p = 0; p < 4; ++p) {
        int arow = m0 + (w * 4 + p) * 8 + lr; if (arow > M - 1) arow = M - 1;
        ga[p] = A + (size_t)arow * K + lc * 8;
    }
#pragma unroll
    for (int p = 0; p < 2; ++p)
        gb[p] = Bt + (size_t)(n0 + (w * 2 + p) * 8 + lr) * K + lc * 8;
    floatx4 acc[4][2] = {};
    const int qr = (w >> 1) * 64, qc = (w & 1) * 32;
    const int lm = lane & 15, lk = lane >> 4;
    for (int k0 = 0; k0 < K; k0 += 64) {
#pragma unroll
        for (int p = 0; p < 4; ++p) { gld16(ga[p], As + (w * 4 + p) * 512); ga[p] += 64; }
#pragma unroll
        for (int p = 0; p < 2; ++p) { gld16(gb[p], Bs + (w * 2 + p) * 512); gb[p] += 64; }
        __syncthreads();
#pragma unroll
        for (int kk = 0; kk < 2; ++kk) {
            int ch = (kk * 4 + lk) ^ (lm & 7);
            short8 af[4], bf[2];
#pragma unroll
            for (int t = 0; t < 4; ++t)
                af[t] = *(const short8*)&As[(qr + t * 16 + lm) * 64 + ch * 8];
#pragma unroll
            for (int t = 0; t < 2; ++t)
                bf[t] = *(const short8*)&Bs[(qc + t * 16 + lm) * 64 + ch * 8];
#pragma unroll
            for (int i = 0; i < 4; ++i)
#pragma unroll
                for (int j = 0; j < 2; ++j)
                    acc[i][j] = MFMA(af[i], bf[j], acc[i][j], 0, 0, 0);
        }
        __syncthreads();
    }
#pragma unroll
    for (int i = 0; i < 4; ++i) {
        int mbase = m0 + qr + i * 16 + (lane >> 4) * 4;
#pragma unroll
        for (int j = 0; j < 2; ++j) {
            int n = n0 + qc + j * 16 + lm;
            float bs = bias[n];
#pragma unroll
            for (int r = 0; r < 4; ++r) {
                int row = mbase + r;
                if (row < M) outF[(size_t)row * N + n] = acc[i][j][r] + bs;
            }
        }
    }
}

// ---------- fused attention v14: v8 pipeline, slimmed to 3 blocks/CU ------
// grid (6, 12, 8), 512 threads (8 waves). LDS 51.25KB -> 3 blocks/CU
// (157.7KB incl overhead; capacity 768 >= 576: single-round makespan).
// vs v8 (76.5KB, 2 blocks, 50us): (a) cc single-buffered -- barrier (1)
// of the next iter already orders PV's reads before next B's writes, the
// dbuf was unnecessary (-9KB, barrier count unchanged at 3/iter);
// (b) qps staging dropped -- dk's A-operand is only 2x16B/lane/iter,
// loaded JIT right after barrier (1) and consumed LAST in phase B, so
// c2c+dq (12 MFMAs + 12 LDS b128 reads) hide the L2 latency (-16KB).
// kt+kps keep v8's DMA staging issued after barrier (2), overlapping
// phases C+D (v13's lesson: synchronous fenced JIT loads serialize).
// No reg cap (v9-v12 lesson: caps force spill); natural ~64-75 regs.
// t=767 overread (i0=0, jt=5) lands in wsT pad; outputs band-masked.
__global__ __launch_bounds__(512, 2) void attn_fused14(
    const ushort* __restrict__ qk, const ushort* __restrict__ vT,
    const ushort* __restrict__ posKQ, ushort* __restrict__ aob)
{
    __shared__ ushort kt[64 * 64];        // 8 KB  k tile (swizzled)
    __shared__ ushort kps[128 * 64];      // 16 KB Kp band (swizzled)
    __shared__ ushort cc[64 * 72];        // 9 KB  c2c scores / P (in-place)
    __shared__ ushort dqs[64 * 72];       // 9 KB  dq pre-shifted: [i][j]=dq[i][j-i+63]
    __shared__ ushort dks[64 * 72];       // 9 KB  dk pre-shifted: [i][j]=dk[j-i+63][j]
    __shared__ float rowsum[64];          // 0.25 KB   (total 51.25 KB)

    const int tid = threadIdx.x;
    const int lane = tid & 63, w = tid >> 6;
    const int i0 = blockIdx.x * 64;
    const int h = blockIdx.y, b = blockIdx.z;
    const int lm = lane & 15, lq = lane >> 4;
    const int lr = lane >> 3, l8 = lane & 7;
    const int lc = l8 ^ (lr & 7);                 // swizzled source chunk
    const int exr = tid >> 3, exseg = tid & 7;    // 64 rows x 8 segs (phase C)

    if (tid < 64) rowsum[tid] = 0.f;

    // q fragments: register-resident (i-tile w>>1; two waves share a tile)
    short8 qf[2];
    {
        const ushort* qr = qk + (size_t)(b * SEQ + i0 + (w >> 1) * 16 + lm) * QKN + h * DH;
        qf[0] = *(const short8*)(qr + lq * 8);
        qf[1] = *(const short8*)(qr + 32 + lq * 8);
    }
    const ushort* kb = qk + 768 + h * DH;
    floatx4 occ[2] = {};

    const int t0i = 320 - i0;
    const int tcb = (w & 1) * 4;

    // stage j-tile 0: kt + kps (DMA)
    {
        gld16(kb + (size_t)(b * SEQ + 8 * w + lr) * QKN + lc * 8, kt + w * 512);
        gld16(posKQ + (size_t)(t0i + 16 * w + lr) * PN + h * DH + lc * 8, kps + w * 1024);
        gld16(posKQ + (size_t)(t0i + 16 * w + 8 + lr) * PN + h * DH + lc * 8, kps + w * 1024 + 512);
    }

    for (int jt = 0; jt < 6; ++jt) {
        const int j0 = jt * 64;
        __syncthreads();        // (1) staging landed; prev C (dqs/dks) + PV (cc) done

        // JIT Qp fragment for dk (consumed last in B; latency hides under c2c+dq)
        short8 qpf[2];
        {
            const ushort* qpb = posKQ + (size_t)(t0i + j0 + w * 16 + lm) * PN
                                + 768 + h * DH + lq * 8;
            qpf[0] = *(const short8*)(qpb);
            qpf[1] = *(const short8*)(qpb + 32);
        }

        // ---- phase B: c2c + dq + dk -> bf16 buffers, unique writers ----
        const int tr = w >> 1;
        { // c2c: i-tile w>>1 x j-tiles (w&1)*2+{0,1}
            int tjb = (w & 1) * 2;
            floatx4 a0 = {}, a1 = {};
#pragma unroll
            for (int kk = 0; kk < 2; ++kk) {
                int ch = (kk * 4 + lq) ^ (lm & 7);
                short8 b0 = *(const short8*)&kt[(tjb * 16 + lm) * 64 + ch * 8];
                short8 b1 = *(const short8*)&kt[((tjb + 1) * 16 + lm) * 64 + ch * 8];
                a0 = MFMA(qf[kk], b0, a0, 0, 0, 0);
                a1 = MFMA(qf[kk], b1, a1, 0, 0, 0);
            }
#pragma unroll
            for (int r = 0; r < 4; ++r) {
                cc[(tr * 16 + lq * 4 + r) * 72 + tjb * 16 + lm] = f2bf(a0[r]);
                cc[(tr * 16 + lq * 4 + r) * 72 + (tjb + 1) * 16 + lm] = f2bf(a1[r]);
            }
        }
        { // dq: i-tile w>>1 x t-tiles (tcb+{0..3}) from staged kps
            floatx4 d[4] = {};
#pragma unroll
            for (int kk = 0; kk < 2; ++kk) {
                int ch = (kk * 4 + lq) ^ (lm & 7);
#pragma unroll
                for (int s = 0; s < 4; ++s) {
                    short8 bf = *(const short8*)&kps[((tcb + s) * 16 + lm) * 64 + ch * 8];
                    d[s] = MFMA(qf[kk], bf, d[s], 0, 0, 0);
                }
            }
#pragma unroll
            for (int s = 0; s < 4; ++s) {
                int t = (tcb + s) * 16 + lm;
#pragma unroll
                for (int r = 0; r < 4; ++r) {
                    int i = tr * 16 + lq * 4 + r;
                    int j = t + i - 63;
                    if ((unsigned)j < 64u) dqs[i * 72 + j] = f2bf(d[s][r]);
                }
            }
        }
        { // dk: t-tile w x j-tiles {0..3}; A-operand = JIT qpf
            floatx4 e[4] = {};
#pragma unroll
            for (int kk = 0; kk < 2; ++kk) {
                int ch = (kk * 4 + lq) ^ (lm & 7);
#pragma unroll
                for (int s = 0; s < 4; ++s) {
                    short8 bf = *(const short8*)&kt[(s * 16 + lm) * 64 + ch * 8];
                    e[s] = MFMA(qpf[kk], bf, e[s], 0, 0, 0);
                }
            }
#pragma unroll
            for (int s = 0; s < 4; ++s) {
                int j = s * 16 + lm;
#pragma unroll
                for (int r = 0; r < 4; ++r) {
                    int t = w * 16 + lq * 4 + r;
                    int i = j - t + 63;
                    if ((unsigned)i < 64u) dks[i * 72 + j] = f2bf(e[s][r]);
                }
            }
        }
        __syncthreads();        // (2) B done; kt/kps free

        // issue next iter's staging (overlaps phases C and D)
        if (jt < 5) {
            int t0n = t0i + j0 + 64;
            gld16(kb + (size_t)(b * SEQ + j0 + 64 + 8 * w + lr) * QKN + lc * 8, kt + w * 512);
            gld16(posKQ + (size_t)(t0n + 16 * w + lr) * PN + h * DH + lc * 8, kps + w * 1024);
            gld16(posKQ + (size_t)(t0n + 16 * w + 8 + lr) * PN + h * DH + lc * 8, kps + w * 1024 + 512);
        }

        // ---- phase C: gather 3 terms (b128), exp, rowsum, P in place ----
        {
            int off = exr * 72 + exseg * 8;
            uint4 c4 = *(const uint4*)&cc[off];
            uint4 q4 = *(const uint4*)&dqs[off];
            uint4 k4 = *(const uint4*)&dks[off];
            const ushort* cu = (const ushort*)&c4;
            const ushort* qu = (const ushort*)&q4;
            const ushort* ku = (const ushort*)&k4;
            float psum = 0.f;
            ushort pv[8];
#pragma unroll
            for (int c = 0; c < 8; ++c) {
                float sv = (bf2f(cu[c]) + bf2f(qu[c]) + bf2f(ku[c])) * 0.125f;
                float pe = __expf(sv);
                psum += pe;
                pv[c] = f2bf(pe);
            }
            psum += __shfl_xor(psum, 1);
            psum += __shfl_xor(psum, 2);
            psum += __shfl_xor(psum, 4);
            if (exseg == 0) rowsum[exr] += psum;
            *(uint4*)&cc[off] = *(uint4*)pv;
        }
        __syncthreads();        // (3) P visible

        // ---- phase D: PV accumulate; v direct-to-register -------------
        {
            int dtb = (w & 1) * 2;
#pragma unroll
            for (int t2 = 0; t2 < 2; ++t2) {
                int dt = dtb + t2;
                const ushort* vr = vT + ((size_t)(b * NH + h) * DH + dt * 16 + lm) * SEQ + j0;
                short8 vf0 = *(const short8*)(vr + lq * 8);
                short8 vf1 = *(const short8*)(vr + 32 + lq * 8);
                short8 af0 = *(const short8*)&cc[(tr * 16 + lm) * 72 + lq * 8];
                short8 af1 = *(const short8*)&cc[(tr * 16 + lm) * 72 + 32 + lq * 8];
                occ[t2] = MFMA(af0, vf0, occ[t2], 0, 0, 0);
                occ[t2] = MFMA(af1, vf1, occ[t2], 0, 0, 0);
            }
        }
        // no barrier: next iter's (1) orders PV's cc reads before next B's writes
    }

    {
        int tr = w >> 1, dtb = (w & 1) * 2;
#pragma unroll
        for (int t2 = 0; t2 < 2; ++t2) {
#pragma unroll
            for (int r = 0; r < 4; ++r) {
                int row = tr * 16 + lq * 4 + r;
                float ov = occ[t2][r] / rowsum[row];
                aob[(size_t)(b * SEQ + i0 + row) * DIM + h * DH + (dtb + t2) * 16 + lm] = f2bf(ov);
            }
        }
    }
}

extern "C" void kernel_launch(void* const* d_in, const int* in_sizes, int n_in,
                              void* d_out, int out_size, void* d_ws, size_t ws_size,
                              hipStream_t stream) {
    const float* x   = (const float*)d_in[0];
    const float* rpe = (const float*)d_in[1];
    const float* Wq  = (const float*)d_in[2];
    const float* bq  = (const float*)d_in[3];
    const float* Wk  = (const float*)d_in[4];
    const float* bk  = (const float*)d_in[5];
    const float* Wv  = (const float*)d_in[6];
    const float* bv  = (const float*)d_in[7];
    const float* qbias = (const float*)d_in[8];
    const float* vbias = (const float*)d_in[9];
    const float* Wpk = (const float*)d_in[10];
    const float* Wpq = (const float*)d_in[11];
    const float* Wo  = (const float*)d_in[12];
    const float* bo  = (const float*)d_in[13];
    float* out = (float*)d_out;

    char* ws = (char*)d_ws;
    ushort* xb    = (ushort*)ws; ws += (size_t)NTOK * DIM * 2;
    ushort* qkbuf = (ushort*)ws; ws += (size_t)NTOK * QKN * 2;
    ushort* vT    = (ushort*)ws; ws += (size_t)NTOK * DIM * 2;
    ushort* aob   = (ushort*)ws; ws += (size_t)NTOK * DIM * 2;
    ushort* rpeb  = (ushort*)ws; ws += (size_t)NPOS * DIM * 2;
    ushort* posKQ = (ushort*)ws; ws += (size_t)NPOS * PN * 2;
    ushort* wsT   = (ushort*)ws; ws += (size_t)6 * DIM * DIM * 2;   // must follow posKQ (t=767 overread pad)

    // 1) converts + weight transposes
    prep<<<dim3(12, 12, 7), dim3(256), 0, stream>>>(
        Wq, Wk, Wv, Wpk, Wpq, Wo, x, rpe, wsT, xb, rpeb);
    // 2) QKV projection + positional projections in one launch (504 blocks)
    proj_all<<<dim3(504), dim3(256), 0, stream>>>(
        xb, rpeb, wsT, bq, qbias, bk, bv, vbias, qkbuf, vT, posKQ);
    // 3) fused attention v14 (51.25KB LDS, 3 blocks/CU, v8 pipeline)
    attn_fused14<<<dim3(SEQ / 64, NH, BATCH), dim3(512), 0, stream>>>(qkbuf, vT, posKQ, aob);
    // 4) output projection -> fp32 d_out (288 blocks)
    gemm128x64<<<dim3(DIM / 64, NTOK / 128), dim3(256), 0, stream>>>(
        aob, wsT + (size_t)5 * DIM * DIM, bo, out, NTOK, DIM, DIM);
}